// Round 3
// baseline (258.088 us; speedup 1.0000x reference)
//
#include <hip/hip_runtime.h>
#include <math.h>

#define Bsz 4
#define Tsz 2048
#define Csz 1024
#define NH  16
#define HD  64

typedef short bf16x8 __attribute__((ext_vector_type(8)));
typedef float f32x4  __attribute__((ext_vector_type(4)));
typedef unsigned short u16;
typedef unsigned int uint;

__device__ __forceinline__ u16 f2bf(float f) {
    union { float f; unsigned u; } v; v.f = f;
    unsigned r = v.u + 0x7fffu + ((v.u >> 16) & 1u);
    return (u16)(r >> 16);
}

__device__ __forceinline__ uint pkbf(float a, float b) {
    union { float f; uint u; } x, y; x.f = a; y.f = b;
    return ((x.u + 0x8000u) >> 16) | ((y.u + 0x8000u) & 0xFFFF0000u);
}

// async global->LDS, 16B per lane. LDS dest is wave-uniform base + lane*16B.
__device__ __forceinline__ void glds16(const u16* g, u16* l) {
    __builtin_amdgcn_global_load_lds(
        (const __attribute__((address_space(1))) void*)g,
        (__attribute__((address_space(3))) void*)l, 16, 0, 0);
}

// ---------------- casts ----------------
__global__ void cast_kernel(const float* __restrict__ src, u16* __restrict__ dst, int n) {
    int i = (blockIdx.x * blockDim.x + threadIdx.x) * 8;
    if (i + 8 <= n) {
        float4 a = *(const float4*)(src + i);
        float4 b = *(const float4*)(src + i + 4);
        bf16x8 o;
        o[0] = (short)f2bf(a.x); o[1] = (short)f2bf(a.y);
        o[2] = (short)f2bf(a.z); o[3] = (short)f2bf(a.w);
        o[4] = (short)f2bf(b.x); o[5] = (short)f2bf(b.y);
        o[6] = (short)f2bf(b.z); o[7] = (short)f2bf(b.w);
        *(bf16x8*)(dst + i) = o;
    } else {
        for (; i < n; i++) dst[i] = f2bf(src[i]);
    }
}

__global__ void cast4_kernel(const float* __restrict__ s0, const float* __restrict__ s1,
                             const float* __restrict__ s2, const float* __restrict__ s3,
                             u16* __restrict__ dst) {
    const int NW = Csz * Csz;
    int i = (blockIdx.x * blockDim.x + threadIdx.x) * 8;
    int m = i >> 20;
    int local = i & (NW - 1);
    const float* src = (m == 0) ? s0 : (m == 1) ? s1 : (m == 2) ? s2 : s3;
    float4 a = *(const float4*)(src + local);
    float4 b = *(const float4*)(src + local + 4);
    bf16x8 o;
    o[0] = (short)f2bf(a.x); o[1] = (short)f2bf(a.y);
    o[2] = (short)f2bf(a.z); o[3] = (short)f2bf(a.w);
    o[4] = (short)f2bf(b.x); o[5] = (short)f2bf(b.y);
    o[6] = (short)f2bf(b.z); o[7] = (short)f2bf(b.w);
    *(bf16x8*)(dst + i) = o;
}

// ================= 128x256 2-phase-per-K-tile GEMM template =================
// BM=128, BN=256, BK=64 (two k-halves of 32). 512 threads = 8 waves (2Mx4N),
// wave tile 64x64 = acc[4][4]. Per phase: read 4 A-frags + 4 B-frags, 16 MFMA.
// LDS: slot = A(16KB) + B(32KB) = 48KB; 2 slots = 96KB -> 1 block/CU.
//
// Stage granularity = one (matrix, khalf): A-half = 1 glds/thread, B-half = 2.
// Schedule: tile t ph0 stages (t+1,kh1,{A,B}) [3 loads]; ph1 stages
// (t+2,kh0,{A,B}) [3 loads]. Prologue: (0,kh0)(0,kh1)(1,kh0) = 9 loads.
// vmcnt ledger (per-wave counts; vmcnt BEFORE the barrier so every wave's own
// loads are complete, barrier publishes cross-wave):
//   t ph0 entry needs (t,kh0); newer outstanding = (t,kh1):3 + (t+1,kh0):3 -> vmcnt(6)
//   t ph1 entry needs (t,kh1); newer = (t+1,kh0):3 + (t+1,kh1):3 -> vmcnt(6)
//   t=15 ph0: newer = (15,kh1):3 -> vmcnt(3); t=15 ph1 -> vmcnt(0)
// Slot WAR: (t+1,kh1)->slot s^1 kh1, last read at t-1 ph1, all waves past t ph0
// barrier. (t+2,kh0)->slot s kh0, read at t ph0, all waves past t ph1 barrier.
// Bank swizzle (T2): 16B chunk c of row r stored at c^((r>>1)&3); applied on the
// glds GLOBAL source (LDS dest linear, rule 21) and XOR'd on the ds_read side.

#define G2_SS 24576   // u16: slot stride (48KB). A kh: SLOT*SS+KH*4096 (128x32)
                      // B kh: SLOT*SS+8192+KH*8192 (256x32)

#define G2_STAGEA(SLOT, KH, KT, PTR) {                                               \
    const int row_ = tid >> 2;                                                       \
    const int sc_ = (tid & 3) ^ ((row_ >> 1) & 3);                                   \
    glds16((PTR) + (size_t)row_ * 1024 + (KT) * 64 + (KH) * 32 + sc_ * 8,            \
           lds + (SLOT) * G2_SS + (KH) * 4096 + wave * 512); }

#define G2_STAGEB(SLOT, KH, KT, PTR) {                                               \
    _Pragma("unroll")                                                                \
    for (int rho = 0; rho < 2; rho++) {                                              \
        const int row_ = rho * 128 + (tid >> 2);                                     \
        const int sc_ = (tid & 3) ^ ((row_ >> 1) & 3);                               \
        glds16((PTR) + (size_t)row_ * 1024 + (KT) * 64 + (KH) * 32 + sc_ * 8,        \
               lds + (SLOT) * G2_SS + 8192 + (KH) * 8192 + rho * 4096 + wave * 512); } }

#define G2_PHASE(SLOT, KH, STAGE)                                                    \
    {                                                                                \
        __builtin_amdgcn_s_barrier();                                                \
        asm volatile("" ::: "memory");                                               \
        STAGE                                                                        \
        const u16* abase = lds + (SLOT) * G2_SS + (KH) * 4096;                       \
        const u16* bbase = lds + (SLOT) * G2_SS + 8192 + (KH) * 8192;                \
        bf16x8 afr[4], bfr[4];                                                       \
        _Pragma("unroll")                                                            \
        for (int i = 0; i < 4; i++) {                                                \
            const int ar = wrb + i * 16 + lr;                                        \
            afr[i] = *(const bf16x8*)(abase + ar * 32 +                              \
                                      ((lq ^ ((ar >> 1) & 3)) * 8));                 \
        }                                                                            \
        _Pragma("unroll")                                                            \
        for (int j = 0; j < 4; j++) {                                                \
            const int nr = wcb + j * 16 + lr;                                        \
            bfr[j] = *(const bf16x8*)(bbase + nr * 32 +                              \
                                      ((lq ^ ((nr >> 1) & 3)) * 8));                 \
        }                                                                            \
        asm volatile("" ::: "memory");                                               \
        __builtin_amdgcn_s_setprio(1);                                               \
        _Pragma("unroll")                                                            \
        for (int i = 0; i < 4; i++)                                                  \
            _Pragma("unroll")                                                        \
            for (int j = 0; j < 4; j++)                                              \
                acc[i][j] = __builtin_amdgcn_mfma_f32_16x16x32_bf16(                 \
                    afr[i], bfr[j], acc[i][j], 0, 0, 0);                             \
        __builtin_amdgcn_s_setprio(0);                                               \
    }

#define G2_VM(N) asm volatile("s_waitcnt vmcnt(" #N ")" ::: "memory")

#define G2_BODY(AP_, BP_)                                                            \
    __shared__ u16 lds[49152];                                                       \
    const int tid = threadIdx.x;                                                     \
    const int wave = tid >> 6, lane = tid & 63;                                      \
    const int lr = lane & 15, lq = lane >> 4;                                        \
    const int wrb = (wave >> 2) * 64, wcb = (wave & 3) * 64;                         \
    f32x4 acc[4][4] = {};                                                            \
    G2_STAGEA(0, 0, 0, AP_) G2_STAGEB(0, 0, 0, BP_)                                  \
    G2_STAGEA(0, 1, 0, AP_) G2_STAGEB(0, 1, 0, BP_)                                  \
    G2_STAGEA(1, 0, 1, AP_) G2_STAGEB(1, 0, 1, BP_)                                  \
    for (int t = 0; t < 16; t++) {                                                   \
        const int s = t & 1;                                                         \
        if (t == 15) { G2_VM(3); } else { G2_VM(6); }                                \
        G2_PHASE(s, 0, if (t < 15) { G2_STAGEA(s ^ 1, 1, t + 1, AP_)                 \
                                     G2_STAGEB(s ^ 1, 1, t + 1, BP_) })              \
        if (t == 15) { G2_VM(0); } else { G2_VM(6); }                                \
        G2_PHASE(s, 1, if (t < 14) { G2_STAGEA(s, 0, t + 2, AP_)                     \
                                     G2_STAGEB(s, 0, t + 2, BP_) })                  \
    }

// ---------------- fused QKV GEMM ----------------
// Grid: 768 flat blocks (64 m-tiles x 12 n-tiles) = 3 FULL dispatch rounds at
// 1 block/CU (no tail). XCD-chunked (768%8==0, bijective): chunk = 16m x 6n,
// n-fastest within (resident ~A 1.4MB + B 3MB ~ L2).
__global__ __launch_bounds__(512, 2)
void gemm_qkv(const u16* __restrict__ A, const u16* __restrict__ Bm,
              u16* __restrict__ Qo, u16* __restrict__ Ko, u16* __restrict__ Vo,
              float qscale) {
    const int wg = blockIdx.x;
    const int chunk = wg & 7, pos = wg >> 3;            // chunk = XCD, pos 0..95
    const int m0 = ((chunk >> 1) * 16 + pos / 6) * 128;
    const int n0 = ((chunk & 1) * 6 + pos % 6) * 256;
    const u16* Ap = A  + (size_t)m0 * 1024;
    const u16* Bp = Bm + (size_t)n0 * 1024;

    G2_BODY(Ap, Bp)

    const int sel = n0 >> 10;   // block-uniform: 0=Q, 1=K, 2=V
    if (sel == 2) {
        #pragma unroll
        for (int mi = 0; mi < 4; mi++) {
            #pragma unroll
            for (int ni = 0; ni < 4; ni++) {
                int m = m0 + wrb + mi * 16 + lq * 4;
                int b = m >> 11, tt = m & (Tsz - 1);
                int n = (n0 & 1023) + wcb + ni * 16 + lr;
                int h = n >> 6, d = n & (HD - 1);
                uint2 pk;
                pk.x = pkbf(acc[mi][ni][0], acc[mi][ni][1]);
                pk.y = pkbf(acc[mi][ni][2], acc[mi][ni][3]);
                *(uint2*)(&Vo[(((size_t)b * NH + h) * HD + d) * Tsz + tt]) = pk;
            }
        }
    } else {
        const float scale = (sel == 0) ? qscale : 1.0f;
        u16* dst = (sel == 0) ? Qo : Ko;
        #pragma unroll
        for (int mi = 0; mi < 4; mi++)
            #pragma unroll
            for (int ni = 0; ni < 4; ni++)
                #pragma unroll
                for (int r = 0; r < 4; r++) {
                    int m = m0 + wrb + mi * 16 + lq * 4 + r;
                    int n = (n0 & 1023) + wcb + ni * 16 + lr;
                    int b = m >> 11, tt = m & (Tsz - 1);
                    int h = n >> 6,  d = n & (HD - 1);
                    dst[(((size_t)b * NH + h) * Tsz + tt) * HD + d] = f2bf(acc[mi][ni][r] * scale);
                }
    }
}

// ---------------- output projection GEMM ----------------
// Grid: 256 blocks (64 m-tiles x 4 n-tiles) = exactly 1 full round (was 0.5).
// Chunk = 8m x 4n per XCD (A 2MB + B 2MB = L2-fit).
__global__ __launch_bounds__(512, 2)
void gemm_out(const u16* __restrict__ A, const u16* __restrict__ Bm,
              float* __restrict__ out) {
    const int wg = blockIdx.x;
    const int chunk = wg & 7, pos = wg >> 3;            // pos 0..31
    const int m0 = (chunk * 8 + (pos >> 2)) * 128;
    const int n0 = (pos & 3) * 256;
    const u16* Ap = A  + (size_t)m0 * 1024;
    const u16* Bp = Bm + (size_t)n0 * 1024;

    G2_BODY(Ap, Bp)

    #pragma unroll
    for (int mi = 0; mi < 4; mi++)
        #pragma unroll
        for (int ni = 0; ni < 4; ni++)
            #pragma unroll
            for (int r = 0; r < 4; r++) {
                int m = m0 + wrb + mi * 16 + lq * 4 + r;
                int n = n0 + wcb + ni * 16 + lr;
                out[(size_t)m * Csz + n] = acc[mi][ni][r];
            }
}

// ---------------- flash attention ----------------
// Round-3 changes vs round-2:
//  - DIAG is now a compile-time literal (PROCESS instantiated per case): the
//    16 cmp+cndmask of the causal mask vanish from all non-diagonal tiles.
//  - T5 s_setprio(1) around the QK^T and PV MFMA clusters (m191: +4-7% attn;
//    blocks are independent -> wave role diversity exists).
#define LDT  72
#define LDTP 68

__global__ __launch_bounds__(256, 4)
void attn_kernel(const u16* __restrict__ Q, const u16* __restrict__ Kb,
                 const u16* __restrict__ Vt, u16* __restrict__ O) {
    __shared__ u16 sK[64 * LDT];
    __shared__ u16 sV[64 * LDT];
    __shared__ u16 sP[4][16 * LDTP];
    const int tid  = threadIdx.x;
    const int wave = tid >> 6, lane = tid & 63;
    const int lr = lane & 15, lq = lane >> 4;
    const int bh = blockIdx.x;           // 0..63  (XCD swizzle: id%8 == bh%8)
    const int qa = blockIdx.y;           // 0..15  (short tile)
    const int qc = 31 - qa;              // 16..31 (long tile)
    const int ta = qa * 64, tc = qc * 64;

    const u16* Qp = Q  + (size_t)bh * Tsz * HD;
    const u16* Kp = Kb + (size_t)bh * Tsz * HD;
    const u16* Vp = Vt + (size_t)bh * HD * Tsz;

    bf16x8 qfA0 = *(const bf16x8*)(Qp + (size_t)(ta + wave * 16 + lr) * HD + lq * 8);
    bf16x8 qfA1 = *(const bf16x8*)(Qp + (size_t)(ta + wave * 16 + lr) * HD + 32 + lq * 8);
    bf16x8 qfC0 = *(const bf16x8*)(Qp + (size_t)(tc + wave * 16 + lr) * HD + lq * 8);
    bf16x8 qfC1 = *(const bf16x8*)(Qp + (size_t)(tc + wave * 16 + lr) * HD + 32 + lq * 8);

    f32x4 accOA[4] = {}, accOC[4] = {};
    f32x4 accLA = {}, accLC = {};

    bf16x8 ones;
    #pragma unroll
    for (int i = 0; i < 8; i++) ones[i] = (short)0x3F80;  // bf16 1.0

    const int strow = tid >> 3;
    const int stcol = (tid & 7) * 8;
    const u16* gK0 = Kp + (size_t)strow * HD + stcol;
    const u16* gK1 = gK0 + 32 * HD;
    const u16* gV0 = Vp + (size_t)strow * Tsz + stcol;
    const u16* gV1 = gV0 + 32 * Tsz;
    u16* lK0 = sK + strow * LDT + stcol;  u16* lK1 = lK0 + 32 * LDT;
    u16* lV0 = sV + strow * LDT + stcol;  u16* lV1 = lV0 + 32 * LDT;

    bf16x8 pK0 = *(const bf16x8*)(gK0);
    bf16x8 pK1 = *(const bf16x8*)(gK1);
    bf16x8 pV0 = *(const bf16x8*)(gV0);
    bf16x8 pV1 = *(const bf16x8*)(gV1);

#define PROCESS(T0, QF0, QF1, ACCO, ACCL, DIAG)                                       \
    {                                                                                 \
        f32x4 accS[4];                                                                \
        __builtin_amdgcn_s_setprio(1);                                                \
        _Pragma("unroll")                                                             \
        for (int j = 0; j < 4; j++) {                                                 \
            bf16x8 b0 = *(const bf16x8*)(sK + (j * 16 + lr) * LDT + lq * 8);          \
            bf16x8 b1 = *(const bf16x8*)(sK + (j * 16 + lr) * LDT + 32 + lq * 8);     \
            f32x4 z = {};                                                             \
            z = __builtin_amdgcn_mfma_f32_16x16x32_bf16(QF0, b0, z, 0, 0, 0);         \
            z = __builtin_amdgcn_mfma_f32_16x16x32_bf16(QF1, b1, z, 0, 0, 0);         \
            accS[j] = z;                                                              \
        }                                                                             \
        __builtin_amdgcn_s_setprio(0);                                                \
        _Pragma("unroll")                                                             \
        for (int r = 0; r < 4; r++) {                                                 \
            const int rowg = (T0) + wave * 16 + lq * 4 + r;                           \
            _Pragma("unroll")                                                         \
            for (int j = 0; j < 4; j++) {                                             \
                float v = accS[j][r];                                                 \
                if (DIAG && (kb * 64 + j * 16 + lr > rowg)) v = -200.0f;              \
                union { float f; uint u; } e;                                         \
                e.f = __builtin_amdgcn_exp2f(v);                                      \
                sP[wave][(lq * 4 + r) * LDTP + j * 16 + lr] = (u16)(e.u >> 16);       \
            }                                                                         \
        }                                                                             \
        __builtin_amdgcn_s_setprio(1);                                                \
        _Pragma("unroll")                                                             \
        for (int ks = 0; ks < 2; ks++) {                                              \
            bf16x8 pf = *(const bf16x8*)(&sP[wave][0] + lr * LDTP + ks * 32 + lq * 8);\
            ACCL = __builtin_amdgcn_mfma_f32_16x16x32_bf16(pf, ones, ACCL, 0, 0, 0);  \
            _Pragma("unroll")                                                         \
            for (int j = 0; j < 4; j++) {                                             \
                bf16x8 vf = *(const bf16x8*)(sV + (j * 16 + lr) * LDT + ks * 32 + lq * 8); \
                ACCO[j] = __builtin_amdgcn_mfma_f32_16x16x32_bf16(pf, vf, ACCO[j], 0, 0, 0); \
            }                                                                         \
        }                                                                             \
        __builtin_amdgcn_s_setprio(0);                                                \
    }

    for (int kb = 0; kb <= qc; kb++) {
        __syncthreads();
        *(bf16x8*)lK0 = pK0; *(bf16x8*)lK1 = pK1;
        *(bf16x8*)lV0 = pV0; *(bf16x8*)lV1 = pV1;
        __syncthreads();
        if (kb < qc) {
            pK0 = *(const bf16x8*)(gK0 + (size_t)(kb + 1) * 64 * HD);
            pK1 = *(const bf16x8*)(gK1 + (size_t)(kb + 1) * 64 * HD);
            pV0 = *(const bf16x8*)(gV0 + (kb + 1) * 64);
            pV1 = *(const bf16x8*)(gV1 + (kb + 1) * 64);
        }
        if (kb < qa) {
            PROCESS(ta, qfA0, qfA1, accOA, accLA, 0)
            PROCESS(tc, qfC0, qfC1, accOC, accLC, 0)
        } else if (kb == qa) {
            PROCESS(ta, qfA0, qfA1, accOA, accLA, 1)
            PROCESS(tc, qfC0, qfC1, accOC, accLC, 0)
        } else if (kb < qc) {
            PROCESS(tc, qfC0, qfC1, accOC, accLC, 0)
        } else {
            PROCESS(tc, qfC0, qfC1, accOC, accLC, 1)
        }
    }
#undef PROCESS

    const int b = bh >> 4, h = bh & 15;
    #pragma unroll
    for (int j = 0; j < 4; j++) {
        #pragma unroll
        for (int r = 0; r < 4; r++) {
            int t = wave * 16 + lq * 4 + r;
            int d = j * 16 + lr;
            O[((size_t)b * Tsz + ta + t) * Csz + h * HD + d] = f2bf(accOA[j][r] / accLA[r]);
            O[((size_t)b * Tsz + tc + t) * Csz + h * HD + d] = f2bf(accOC[j][r] / accLC[r]);
        }
    }
}

// ---------------- launcher ----------------
extern "C" void kernel_launch(void* const* d_in, const int* in_sizes, int n_in,
                              void* d_out, int out_size, void* d_ws, size_t ws_size,
                              hipStream_t stream) {
    const float* x  = (const float*)d_in[0];
    const float* Wq = (const float*)d_in[1];
    const float* Wk = (const float*)d_in[2];
    const float* Wv = (const float*)d_in[3];
    const float* Wo = (const float*)d_in[4];
    float* out = (float*)d_out;

    const size_t NX = (size_t)Bsz * Tsz * Csz;  // 8388608
    const size_t NW = (size_t)Csz * Csz;        // 1048576

    char* ws = (char*)d_ws;
    u16* xb   = (u16*)ws; ws += NX * 2;
    u16* wqkv = (u16*)ws; ws += 3 * NW * 2;
    u16* wob  = (u16*)ws; ws += NW * 2;         // contiguous after wqkv (cast4 target)
    u16* qbuf = (u16*)ws; ws += NX * 2;
    u16* kbuf = (u16*)ws; ws += NX * 2;
    u16* vtb  = (u16*)ws; ws += NX * 2;
    u16* abuf = (u16*)ws; ws += NX * 2;

    cast_kernel<<<dim3((unsigned)(NX / 2048)), 256, 0, stream>>>(x, xb, (int)NX);
    cast4_kernel<<<dim3((unsigned)(4 * NW / 2048)), 256, 0, stream>>>(Wq, Wk, Wv, Wo, wqkv);

    const float qscale = 0.125f * 1.44269504088896340736f;  // 1/sqrt(64) * log2(e)
    gemm_qkv<<<dim3(768), 512, 0, stream>>>(xb, wqkv, qbuf, kbuf, vtb, qscale);

    attn_kernel<<<dim3(Bsz * NH, 16), 256, 0, stream>>>(qbuf, kbuf, vtb, abuf);

    gemm_out<<<dim3(256), 512, 0, stream>>>(abuf, wob, out);
}

// Round 4
// 248.736 us; speedup vs baseline: 1.0376x; 1.0376x over previous
//
#include <hip/hip_runtime.h>
#include <math.h>

#define Bsz 4
#define Tsz 2048
#define Csz 1024
#define NH  16
#define HD  64

typedef short bf16x8 __attribute__((ext_vector_type(8)));
typedef float f32x4  __attribute__((ext_vector_type(4)));
typedef unsigned short u16;
typedef unsigned int uint;

__device__ __forceinline__ u16 f2bf(float f) {
    union { float f; unsigned u; } v; v.f = f;
    unsigned r = v.u + 0x7fffu + ((v.u >> 16) & 1u);
    return (u16)(r >> 16);
}

__device__ __forceinline__ uint pkbf(float a, float b) {
    union { float f; uint u; } x, y; x.f = a; y.f = b;
    return ((x.u + 0x8000u) >> 16) | ((y.u + 0x8000u) & 0xFFFF0000u);
}

// async global->LDS, 16B per lane. LDS dest is wave-uniform base + lane*16B.
__device__ __forceinline__ void glds16(const u16* g, u16* l) {
    __builtin_amdgcn_global_load_lds(
        (const __attribute__((address_space(1))) void*)g,
        (__attribute__((address_space(3))) void*)l, 16, 0, 0);
}

// ---------------- fused cast (x + 4 weight matrices, one launch) ----------------
// NX/8 elements-per-thread boundary = 1048576 = block 4096 exactly, so the
// source-select branch is block-uniform.
__global__ void cast_all(const float* __restrict__ x,
                         const float* __restrict__ s0, const float* __restrict__ s1,
                         const float* __restrict__ s2, const float* __restrict__ s3,
                         u16* __restrict__ xb, u16* __restrict__ wdst) {
    const int NW = Csz * Csz;
    const size_t NX = (size_t)Bsz * Tsz * Csz;
    size_t i = ((size_t)blockIdx.x * blockDim.x + threadIdx.x) * 8;
    const float* src;
    u16* dst;
    if (i < NX) {
        src = x + i; dst = xb + i;
    } else {
        size_t j = i - NX;
        int m = (int)(j >> 20);
        size_t local = j & (NW - 1);
        src = ((m == 0) ? s0 : (m == 1) ? s1 : (m == 2) ? s2 : s3) + local;
        dst = wdst + j;
    }
    float4 a = *(const float4*)(src);
    float4 b = *(const float4*)(src + 4);
    bf16x8 o;
    o[0] = (short)f2bf(a.x); o[1] = (short)f2bf(a.y);
    o[2] = (short)f2bf(a.z); o[3] = (short)f2bf(a.w);
    o[4] = (short)f2bf(b.x); o[5] = (short)f2bf(b.y);
    o[6] = (short)f2bf(b.z); o[7] = (short)f2bf(b.w);
    *(bf16x8*)(dst) = o;
}

// ================= 128x256 2-phase-per-K-tile GEMM template =================
// BM=128, BN=256, BK=64 (two k-halves of 32). 512 threads = 8 waves (2Mx4N),
// wave tile 64x64 = acc[4][4]. Per phase: read 4 A-frags + 4 B-frags, 16 MFMA.
// LDS: slot = A(16KB) + B(32KB) = 48KB; 2 slots = 96KB -> 1 block/CU.
//
// Stage granularity = one (matrix, khalf): A-half = 1 glds/thread, B-half = 2.
// Schedule: tile t ph0 stages (t+1,kh1,{A,B}) [3 loads]; ph1 stages
// (t+2,kh0,{A,B}) [3 loads]. Prologue: (0,kh0)(0,kh1)(1,kh0) = 9 loads.
// vmcnt ledger (per-wave counts; vmcnt BEFORE the barrier so every wave's own
// loads are complete, barrier publishes cross-wave):
//   t ph0 entry needs (t,kh0); newer outstanding = (t,kh1):3 + (t+1,kh0):3 -> vmcnt(6)
//   t ph1 entry needs (t,kh1); newer = (t+1,kh0):3 + (t+1,kh1):3 -> vmcnt(6)
//   t=15 ph0: newer = (15,kh1):3 -> vmcnt(3); t=15 ph1 -> vmcnt(0)
// Slot WAR: (t+1,kh1)->slot s^1 kh1, last read at t-1 ph1, all waves past t ph0
// barrier. (t+2,kh0)->slot s kh0, read at t ph0, all waves past t ph1 barrier.
// Bank swizzle (T2): 16B chunk c of row r stored at c^((r>>1)&3); applied on the
// glds GLOBAL source (LDS dest linear, rule 21) and XOR'd on the ds_read side.

#define G2_SS 24576   // u16: slot stride (48KB). A kh: SLOT*SS+KH*4096 (128x32)
                      // B kh: SLOT*SS+8192+KH*8192 (256x32)

#define G2_STAGEA(SLOT, KH, KT, PTR) {                                               \
    const int row_ = tid >> 2;                                                       \
    const int sc_ = (tid & 3) ^ ((row_ >> 1) & 3);                                   \
    glds16((PTR) + (size_t)row_ * 1024 + (KT) * 64 + (KH) * 32 + sc_ * 8,            \
           lds + (SLOT) * G2_SS + (KH) * 4096 + wave * 512); }

#define G2_STAGEB(SLOT, KH, KT, PTR) {                                               \
    _Pragma("unroll")                                                                \
    for (int rho = 0; rho < 2; rho++) {                                              \
        const int row_ = rho * 128 + (tid >> 2);                                     \
        const int sc_ = (tid & 3) ^ ((row_ >> 1) & 3);                               \
        glds16((PTR) + (size_t)row_ * 1024 + (KT) * 64 + (KH) * 32 + sc_ * 8,        \
               lds + (SLOT) * G2_SS + 8192 + (KH) * 8192 + rho * 4096 + wave * 512); } }

#define G2_PHASE(SLOT, KH, STAGE)                                                    \
    {                                                                                \
        __builtin_amdgcn_s_barrier();                                                \
        asm volatile("" ::: "memory");                                               \
        STAGE                                                                        \
        const u16* abase = lds + (SLOT) * G2_SS + (KH) * 4096;                       \
        const u16* bbase = lds + (SLOT) * G2_SS + 8192 + (KH) * 8192;                \
        bf16x8 afr[4], bfr[4];                                                       \
        _Pragma("unroll")                                                            \
        for (int i = 0; i < 4; i++) {                                                \
            const int ar = wrb + i * 16 + lr;                                        \
            afr[i] = *(const bf16x8*)(abase + ar * 32 +                              \
                                      ((lq ^ ((ar >> 1) & 3)) * 8));                 \
        }                                                                            \
        _Pragma("unroll")                                                            \
        for (int j = 0; j < 4; j++) {                                                \
            const int nr = wcb + j * 16 + lr;                                        \
            bfr[j] = *(const bf16x8*)(bbase + nr * 32 +                              \
                                      ((lq ^ ((nr >> 1) & 3)) * 8));                 \
        }                                                                            \
        asm volatile("" ::: "memory");                                               \
        __builtin_amdgcn_s_setprio(1);                                               \
        _Pragma("unroll")                                                            \
        for (int i = 0; i < 4; i++)                                                  \
            _Pragma("unroll")                                                        \
            for (int j = 0; j < 4; j++)                                              \
                acc[i][j] = __builtin_amdgcn_mfma_f32_16x16x32_bf16(                 \
                    afr[i], bfr[j], acc[i][j], 0, 0, 0);                             \
        __builtin_amdgcn_s_setprio(0);                                               \
    }

#define G2_VM(N) asm volatile("s_waitcnt vmcnt(" #N ")" ::: "memory")

#define G2_BODY(AP_, BP_)                                                            \
    __shared__ u16 lds[49152];                                                       \
    const int tid = threadIdx.x;                                                     \
    const int wave = tid >> 6, lane = tid & 63;                                      \
    const int lr = lane & 15, lq = lane >> 4;                                        \
    const int wrb = (wave >> 2) * 64, wcb = (wave & 3) * 64;                         \
    f32x4 acc[4][4] = {};                                                            \
    G2_STAGEA(0, 0, 0, AP_) G2_STAGEB(0, 0, 0, BP_)                                  \
    G2_STAGEA(0, 1, 0, AP_) G2_STAGEB(0, 1, 0, BP_)                                  \
    G2_STAGEA(1, 0, 1, AP_) G2_STAGEB(1, 0, 1, BP_)                                  \
    for (int t = 0; t < 16; t++) {                                                   \
        const int s = t & 1;                                                         \
        if (t == 15) { G2_VM(3); } else { G2_VM(6); }                                \
        G2_PHASE(s, 0, if (t < 15) { G2_STAGEA(s ^ 1, 1, t + 1, AP_)                 \
                                     G2_STAGEB(s ^ 1, 1, t + 1, BP_) })              \
        if (t == 15) { G2_VM(0); } else { G2_VM(6); }                                \
        G2_PHASE(s, 1, if (t < 14) { G2_STAGEA(s, 0, t + 2, AP_)                     \
                                     G2_STAGEB(s, 0, t + 2, BP_) })                  \
    }

// ---------------- fused QKV GEMM ----------------
// Grid: 768 flat blocks (64 m-tiles x 12 n-tiles) = 3 FULL dispatch rounds at
// 1 block/CU (no tail). XCD-chunked (768%8==0, bijective): chunk = 16m x 6n,
// n-fastest within (resident ~A 1.4MB + B 3MB ~ L2).
__global__ __launch_bounds__(512, 2)
void gemm_qkv(const u16* __restrict__ A, const u16* __restrict__ Bm,
              u16* __restrict__ Qo, u16* __restrict__ Ko, u16* __restrict__ Vo,
              float qscale) {
    const int wg = blockIdx.x;
    const int chunk = wg & 7, pos = wg >> 3;            // chunk = XCD, pos 0..95
    const int m0 = ((chunk >> 1) * 16 + pos / 6) * 128;
    const int n0 = ((chunk & 1) * 6 + pos % 6) * 256;
    const u16* Ap = A  + (size_t)m0 * 1024;
    const u16* Bp = Bm + (size_t)n0 * 1024;

    G2_BODY(Ap, Bp)

    const int sel = n0 >> 10;   // block-uniform: 0=Q, 1=K, 2=V
    if (sel == 2) {
        #pragma unroll
        for (int mi = 0; mi < 4; mi++) {
            #pragma unroll
            for (int ni = 0; ni < 4; ni++) {
                int m = m0 + wrb + mi * 16 + lq * 4;
                int b = m >> 11, tt = m & (Tsz - 1);
                int n = (n0 & 1023) + wcb + ni * 16 + lr;
                int h = n >> 6, d = n & (HD - 1);
                uint2 pk;
                pk.x = pkbf(acc[mi][ni][0], acc[mi][ni][1]);
                pk.y = pkbf(acc[mi][ni][2], acc[mi][ni][3]);
                *(uint2*)(&Vo[(((size_t)b * NH + h) * HD + d) * Tsz + tt]) = pk;
            }
        }
    } else {
        const float scale = (sel == 0) ? qscale : 1.0f;
        u16* dst = (sel == 0) ? Qo : Ko;
        #pragma unroll
        for (int mi = 0; mi < 4; mi++)
            #pragma unroll
            for (int ni = 0; ni < 4; ni++)
                #pragma unroll
                for (int r = 0; r < 4; r++) {
                    int m = m0 + wrb + mi * 16 + lq * 4 + r;
                    int n = (n0 & 1023) + wcb + ni * 16 + lr;
                    int b = m >> 11, tt = m & (Tsz - 1);
                    int h = n >> 6,  d = n & (HD - 1);
                    dst[(((size_t)b * NH + h) * Tsz + tt) * HD + d] = f2bf(acc[mi][ni][r] * scale);
                }
    }
}

// ---------------- output projection GEMM ----------------
// Grid: 256 blocks (64 m-tiles x 4 n-tiles) = exactly 1 full round.
// Chunk = 8m x 4n per XCD (A 2MB + B 2MB = L2-fit).
__global__ __launch_bounds__(512, 2)
void gemm_out(const u16* __restrict__ A, const u16* __restrict__ Bm,
              float* __restrict__ out) {
    const int wg = blockIdx.x;
    const int chunk = wg & 7, pos = wg >> 3;            // pos 0..31
    const int m0 = (chunk * 8 + (pos >> 2)) * 128;
    const int n0 = (pos & 3) * 256;
    const u16* Ap = A  + (size_t)m0 * 1024;
    const u16* Bp = Bm + (size_t)n0 * 1024;

    G2_BODY(Ap, Bp)

    #pragma unroll
    for (int mi = 0; mi < 4; mi++)
        #pragma unroll
        for (int ni = 0; ni < 4; ni++)
            #pragma unroll
            for (int r = 0; r < 4; r++) {
                int m = m0 + wrb + mi * 16 + lq * 4 + r;
                int n = n0 + wcb + ni * 16 + lr;
                out[(size_t)m * Csz + n] = acc[mi][ni][r];
            }
}

// ---------------- flash attention (round-2 version, exact revert) ----------------
// Round-3's compile-time-DIAG (6x PROCESS instantiation, I-cache blowup) and
// setprio (lockstep 4-wave block = m190 null/negative regime) both reverted:
// measured 76.5 -> 88 us. This is the measured-76.5 us version.
#define LDT  72
#define LDTP 68

__global__ __launch_bounds__(256, 4)
void attn_kernel(const u16* __restrict__ Q, const u16* __restrict__ Kb,
                 const u16* __restrict__ Vt, u16* __restrict__ O) {
    __shared__ u16 sK[64 * LDT];
    __shared__ u16 sV[64 * LDT];
    __shared__ u16 sP[4][16 * LDTP];
    const int tid  = threadIdx.x;
    const int wave = tid >> 6, lane = tid & 63;
    const int lr = lane & 15, lq = lane >> 4;
    const int bh = blockIdx.x;           // 0..63  (XCD swizzle: id%8 == bh%8)
    const int qa = blockIdx.y;           // 0..15  (short tile)
    const int qc = 31 - qa;              // 16..31 (long tile)
    const int ta = qa * 64, tc = qc * 64;

    const u16* Qp = Q  + (size_t)bh * Tsz * HD;
    const u16* Kp = Kb + (size_t)bh * Tsz * HD;
    const u16* Vp = Vt + (size_t)bh * HD * Tsz;

    bf16x8 qfA0 = *(const bf16x8*)(Qp + (size_t)(ta + wave * 16 + lr) * HD + lq * 8);
    bf16x8 qfA1 = *(const bf16x8*)(Qp + (size_t)(ta + wave * 16 + lr) * HD + 32 + lq * 8);
    bf16x8 qfC0 = *(const bf16x8*)(Qp + (size_t)(tc + wave * 16 + lr) * HD + lq * 8);
    bf16x8 qfC1 = *(const bf16x8*)(Qp + (size_t)(tc + wave * 16 + lr) * HD + 32 + lq * 8);

    f32x4 accOA[4] = {}, accOC[4] = {};
    f32x4 accLA = {}, accLC = {};

    bf16x8 ones;
    #pragma unroll
    for (int i = 0; i < 8; i++) ones[i] = (short)0x3F80;  // bf16 1.0

    const int strow = tid >> 3;
    const int stcol = (tid & 7) * 8;
    const u16* gK0 = Kp + (size_t)strow * HD + stcol;
    const u16* gK1 = gK0 + 32 * HD;
    const u16* gV0 = Vp + (size_t)strow * Tsz + stcol;
    const u16* gV1 = gV0 + 32 * Tsz;
    u16* lK0 = sK + strow * LDT + stcol;  u16* lK1 = lK0 + 32 * LDT;
    u16* lV0 = sV + strow * LDT + stcol;  u16* lV1 = lV0 + 32 * LDT;

    bf16x8 pK0 = *(const bf16x8*)(gK0);
    bf16x8 pK1 = *(const bf16x8*)(gK1);
    bf16x8 pV0 = *(const bf16x8*)(gV0);
    bf16x8 pV1 = *(const bf16x8*)(gV1);

#define PROCESS(T0, QF0, QF1, ACCO, ACCL, DIAG)                                       \
    {                                                                                 \
        f32x4 accS[4];                                                                \
        _Pragma("unroll")                                                             \
        for (int j = 0; j < 4; j++) {                                                 \
            bf16x8 b0 = *(const bf16x8*)(sK + (j * 16 + lr) * LDT + lq * 8);          \
            bf16x8 b1 = *(const bf16x8*)(sK + (j * 16 + lr) * LDT + 32 + lq * 8);     \
            f32x4 z = {};                                                             \
            z = __builtin_amdgcn_mfma_f32_16x16x32_bf16(QF0, b0, z, 0, 0, 0);         \
            z = __builtin_amdgcn_mfma_f32_16x16x32_bf16(QF1, b1, z, 0, 0, 0);         \
            accS[j] = z;                                                              \
        }                                                                             \
        _Pragma("unroll")                                                             \
        for (int r = 0; r < 4; r++) {                                                 \
            const int rowg = (T0) + wave * 16 + lq * 4 + r;                           \
            _Pragma("unroll")                                                         \
            for (int j = 0; j < 4; j++) {                                             \
                float v = accS[j][r];                                                 \
                if (DIAG && (kb * 64 + j * 16 + lr > rowg)) v = -200.0f;              \
                union { float f; uint u; } e;                                         \
                e.f = __builtin_amdgcn_exp2f(v);                                      \
                sP[wave][(lq * 4 + r) * LDTP + j * 16 + lr] = (u16)(e.u >> 16);       \
            }                                                                         \
        }                                                                             \
        _Pragma("unroll")                                                             \
        for (int ks = 0; ks < 2; ks++) {                                              \
            bf16x8 pf = *(const bf16x8*)(&sP[wave][0] + lr * LDTP + ks * 32 + lq * 8);\
            ACCL = __builtin_amdgcn_mfma_f32_16x16x32_bf16(pf, ones, ACCL, 0, 0, 0);  \
            _Pragma("unroll")                                                         \
            for (int j = 0; j < 4; j++) {                                             \
                bf16x8 vf = *(const bf16x8*)(sV + (j * 16 + lr) * LDT + ks * 32 + lq * 8); \
                ACCO[j] = __builtin_amdgcn_mfma_f32_16x16x32_bf16(pf, vf, ACCO[j], 0, 0, 0); \
            }                                                                         \
        }                                                                             \
    }

    for (int kb = 0; kb <= qc; kb++) {
        __syncthreads();
        *(bf16x8*)lK0 = pK0; *(bf16x8*)lK1 = pK1;
        *(bf16x8*)lV0 = pV0; *(bf16x8*)lV1 = pV1;
        __syncthreads();
        if (kb < qc) {
            pK0 = *(const bf16x8*)(gK0 + (size_t)(kb + 1) * 64 * HD);
            pK1 = *(const bf16x8*)(gK1 + (size_t)(kb + 1) * 64 * HD);
            pV0 = *(const bf16x8*)(gV0 + (kb + 1) * 64);
            pV1 = *(const bf16x8*)(gV1 + (kb + 1) * 64);
        }
        if (kb <= qa) PROCESS(ta, qfA0, qfA1, accOA, accLA, (kb == qa));
        PROCESS(tc, qfC0, qfC1, accOC, accLC, (kb == qc));
    }
#undef PROCESS

    const int b = bh >> 4, h = bh & 15;
    #pragma unroll
    for (int j = 0; j < 4; j++) {
        #pragma unroll
        for (int r = 0; r < 4; r++) {
            int t = wave * 16 + lq * 4 + r;
            int d = j * 16 + lr;
            O[((size_t)b * Tsz + ta + t) * Csz + h * HD + d] = f2bf(accOA[j][r] / accLA[r]);
            O[((size_t)b * Tsz + tc + t) * Csz + h * HD + d] = f2bf(accOC[j][r] / accLC[r]);
        }
    }
}

// ---------------- launcher ----------------
extern "C" void kernel_launch(void* const* d_in, const int* in_sizes, int n_in,
                              void* d_out, int out_size, void* d_ws, size_t ws_size,
                              hipStream_t stream) {
    const float* x  = (const float*)d_in[0];
    const float* Wq = (const float*)d_in[1];
    const float* Wk = (const float*)d_in[2];
    const float* Wv = (const float*)d_in[3];
    const float* Wo = (const float*)d_in[4];
    float* out = (float*)d_out;

    const size_t NX = (size_t)Bsz * Tsz * Csz;  // 8388608
    const size_t NW = (size_t)Csz * Csz;        // 1048576

    char* ws = (char*)d_ws;
    u16* xb   = (u16*)ws; ws += NX * 2;
    u16* wqkv = (u16*)ws; ws += 3 * NW * 2;
    u16* wob  = (u16*)ws; ws += NW * 2;         // contiguous after wqkv (cast target)
    u16* qbuf = (u16*)ws; ws += NX * 2;
    u16* kbuf = (u16*)ws; ws += NX * 2;
    u16* vtb  = (u16*)ws; ws += NX * 2;
    u16* abuf = (u16*)ws; ws += NX * 2;

    cast_all<<<dim3((unsigned)((NX + 4 * NW) / 2048)), 256, 0, stream>>>(
        x, Wq, Wk, Wv, Wo, xb, wqkv);

    const float qscale = 0.125f * 1.44269504088896340736f;  // 1/sqrt(64) * log2(e)
    gemm_qkv<<<dim3(768), 512, 0, stream>>>(xb, wqkv, qbuf, kbuf, vtb, qscale);

    attn_kernel<<<dim3(Bsz * NH, 16), 256, 0, stream>>>(qbuf, kbuf, vtb, abuf);

    gemm_out<<<dim3(256), 512, 0, stream>>>(abuf, wob, out);
}

// Round 5
// 245.322 us; speedup vs baseline: 1.0520x; 1.0139x over previous
//
#include <hip/hip_runtime.h>
#include <math.h>

#define Bsz 4
#define Tsz 2048
#define Csz 1024
#define NH  16
#define HD  64

typedef short bf16x8 __attribute__((ext_vector_type(8)));
typedef float f32x4  __attribute__((ext_vector_type(4)));
typedef unsigned short u16;
typedef unsigned int uint;

__device__ __forceinline__ u16 f2bf(float f) {
    union { float f; unsigned u; } v; v.f = f;
    unsigned r = v.u + 0x7fffu + ((v.u >> 16) & 1u);
    return (u16)(r >> 16);
}

__device__ __forceinline__ uint pkbf(float a, float b) {
    union { float f; uint u; } x, y; x.f = a; y.f = b;
    return ((x.u + 0x8000u) >> 16) | ((y.u + 0x8000u) & 0xFFFF0000u);
}

// async global->LDS, 16B per lane. LDS dest is wave-uniform base + lane*16B.
__device__ __forceinline__ void glds16(const u16* g, u16* l) {
    __builtin_amdgcn_global_load_lds(
        (const __attribute__((address_space(1))) void*)g,
        (__attribute__((address_space(3))) void*)l, 16, 0, 0);
}

// ---------------- fused cast (x + 4 weight matrices, one launch) ----------------
// NX/8 elements-per-thread boundary = 1048576 = block 4096 exactly, so the
// source-select branch is block-uniform.
__global__ void cast_all(const float* __restrict__ x,
                         const float* __restrict__ s0, const float* __restrict__ s1,
                         const float* __restrict__ s2, const float* __restrict__ s3,
                         u16* __restrict__ xb, u16* __restrict__ wdst) {
    const int NW = Csz * Csz;
    const size_t NX = (size_t)Bsz * Tsz * Csz;
    size_t i = ((size_t)blockIdx.x * blockDim.x + threadIdx.x) * 8;
    const float* src;
    u16* dst;
    if (i < NX) {
        src = x + i; dst = xb + i;
    } else {
        size_t j = i - NX;
        int m = (int)(j >> 20);
        size_t local = j & (NW - 1);
        src = ((m == 0) ? s0 : (m == 1) ? s1 : (m == 2) ? s2 : s3) + local;
        dst = wdst + j;
    }
    float4 a = *(const float4*)(src);
    float4 b = *(const float4*)(src + 4);
    bf16x8 o;
    o[0] = (short)f2bf(a.x); o[1] = (short)f2bf(a.y);
    o[2] = (short)f2bf(a.z); o[3] = (short)f2bf(a.w);
    o[4] = (short)f2bf(b.x); o[5] = (short)f2bf(b.y);
    o[6] = (short)f2bf(b.z); o[7] = (short)f2bf(b.w);
    *(bf16x8*)(dst) = o;
}

// ================= 128x256 2-phase-per-K-tile GEMM template =================
// BM=128, BN=256, BK=64 (two k-halves of 32). 512 threads = 8 waves (2Mx4N),
// wave tile 64x64 = acc[4][4]. Per phase: read 4 A-frags + 4 B-frags, 16 MFMA.
// LDS: slot = A(16KB) + B(32KB) = 48KB; 2 slots = 96KB -> 1 block/CU.
//
// Stage granularity = one (matrix, khalf): A-half = 1 glds/thread, B-half = 2.
// Schedule: tile t ph0 stages (t+1,kh1,{A,B}) [3 loads]; ph1 stages
// (t+2,kh0,{A,B}) [3 loads]. Prologue: (0,kh0)(0,kh1)(1,kh0) = 9 loads.
// vmcnt ledger (per-wave counts; vmcnt BEFORE the barrier so every wave's own
// loads are complete, barrier publishes cross-wave):
//   t ph0 entry needs (t,kh0); newer outstanding = (t,kh1):3 + (t+1,kh0):3 -> vmcnt(6)
//   t ph1 entry needs (t,kh1); newer = (t+1,kh0):3 + (t+1,kh1):3 -> vmcnt(6)
//   t=15 ph0: newer = (15,kh1):3 -> vmcnt(3); t=15 ph1 -> vmcnt(0)
// Slot WAR: (t+1,kh1)->slot s^1 kh1, last read at t-1 ph1, all waves past t ph0
// barrier. (t+2,kh0)->slot s kh0, read at t ph0, all waves past t ph1 barrier.
// Bank swizzle (T2): 16B chunk c of row r stored at c^((r>>1)&3); applied on the
// glds GLOBAL source (LDS dest linear, rule 21) and XOR'd on the ds_read side.

#define G2_SS 24576   // u16: slot stride (48KB). A kh: SLOT*SS+KH*4096 (128x32)
                      // B kh: SLOT*SS+8192+KH*8192 (256x32)

#define G2_STAGEA(SLOT, KH, KT, PTR) {                                               \
    const int row_ = tid >> 2;                                                       \
    const int sc_ = (tid & 3) ^ ((row_ >> 1) & 3);                                   \
    glds16((PTR) + (size_t)row_ * 1024 + (KT) * 64 + (KH) * 32 + sc_ * 8,            \
           lds + (SLOT) * G2_SS + (KH) * 4096 + wave * 512); }

#define G2_STAGEB(SLOT, KH, KT, PTR) {                                               \
    _Pragma("unroll")                                                                \
    for (int rho = 0; rho < 2; rho++) {                                              \
        const int row_ = rho * 128 + (tid >> 2);                                     \
        const int sc_ = (tid & 3) ^ ((row_ >> 1) & 3);                               \
        glds16((PTR) + (size_t)row_ * 1024 + (KT) * 64 + (KH) * 32 + sc_ * 8,        \
               lds + (SLOT) * G2_SS + 8192 + (KH) * 8192 + rho * 4096 + wave * 512); } }

#define G2_PHASE(SLOT, KH, STAGE)                                                    \
    {                                                                                \
        __builtin_amdgcn_s_barrier();                                                \
        asm volatile("" ::: "memory");                                               \
        STAGE                                                                        \
        const u16* abase = lds + (SLOT) * G2_SS + (KH) * 4096;                       \
        const u16* bbase = lds + (SLOT) * G2_SS + 8192 + (KH) * 8192;                \
        bf16x8 afr[4], bfr[4];                                                       \
        _Pragma("unroll")                                                            \
        for (int i = 0; i < 4; i++) {                                                \
            const int ar = wrb + i * 16 + lr;                                        \
            afr[i] = *(const bf16x8*)(abase + ar * 32 +                              \
                                      ((lq ^ ((ar >> 1) & 3)) * 8));                 \
        }                                                                            \
        _Pragma("unroll")                                                            \
        for (int j = 0; j < 4; j++) {                                                \
            const int nr = wcb + j * 16 + lr;                                        \
            bfr[j] = *(const bf16x8*)(bbase + nr * 32 +                              \
                                      ((lq ^ ((nr >> 1) & 3)) * 8));                 \
        }                                                                            \
        asm volatile("" ::: "memory");                                               \
        __builtin_amdgcn_s_setprio(1);                                               \
        _Pragma("unroll")                                                            \
        for (int i = 0; i < 4; i++)                                                  \
            _Pragma("unroll")                                                        \
            for (int j = 0; j < 4; j++)                                              \
                acc[i][j] = __builtin_amdgcn_mfma_f32_16x16x32_bf16(                 \
                    afr[i], bfr[j], acc[i][j], 0, 0, 0);                             \
        __builtin_amdgcn_s_setprio(0);                                               \
    }

#define G2_VM(N) asm volatile("s_waitcnt vmcnt(" #N ")" ::: "memory")

#define G2_BODY(AP_, BP_)                                                            \
    __shared__ u16 lds[49152];                                                       \
    const int tid = threadIdx.x;                                                     \
    const int wave = tid >> 6, lane = tid & 63;                                      \
    const int lr = lane & 15, lq = lane >> 4;                                        \
    const int wrb = (wave >> 2) * 64, wcb = (wave & 3) * 64;                         \
    f32x4 acc[4][4] = {};                                                            \
    G2_STAGEA(0, 0, 0, AP_) G2_STAGEB(0, 0, 0, BP_)                                  \
    G2_STAGEA(0, 1, 0, AP_) G2_STAGEB(0, 1, 0, BP_)                                  \
    G2_STAGEA(1, 0, 1, AP_) G2_STAGEB(1, 0, 1, BP_)                                  \
    for (int t = 0; t < 16; t++) {                                                   \
        const int s = t & 1;                                                         \
        if (t == 15) { G2_VM(3); } else { G2_VM(6); }                                \
        G2_PHASE(s, 0, if (t < 15) { G2_STAGEA(s ^ 1, 1, t + 1, AP_)                 \
                                     G2_STAGEB(s ^ 1, 1, t + 1, BP_) })              \
        if (t == 15) { G2_VM(0); } else { G2_VM(6); }                                \
        G2_PHASE(s, 1, if (t < 14) { G2_STAGEA(s, 0, t + 2, AP_)                     \
                                     G2_STAGEB(s, 0, t + 2, BP_) })                  \
    }

// ---------------- fused QKV GEMM ----------------
// Grid: 768 flat blocks (64 m-tiles x 12 n-tiles) = 3 FULL dispatch rounds at
// 1 block/CU (no tail). XCD-chunked (768%8==0, bijective): chunk = 16m x 6n,
// n-fastest within (resident ~A 1.4MB + B 3MB ~ L2).
__global__ __launch_bounds__(512, 2)
void gemm_qkv(const u16* __restrict__ A, const u16* __restrict__ Bm,
              u16* __restrict__ Qo, u16* __restrict__ Ko, u16* __restrict__ Vo,
              float qscale) {
    const int wg = blockIdx.x;
    const int chunk = wg & 7, pos = wg >> 3;            // chunk = XCD, pos 0..95
    const int m0 = ((chunk >> 1) * 16 + pos / 6) * 128;
    const int n0 = ((chunk & 1) * 6 + pos % 6) * 256;
    const u16* Ap = A  + (size_t)m0 * 1024;
    const u16* Bp = Bm + (size_t)n0 * 1024;

    G2_BODY(Ap, Bp)

    const int sel = n0 >> 10;   // block-uniform: 0=Q, 1=K, 2=V
    if (sel == 2) {
        #pragma unroll
        for (int mi = 0; mi < 4; mi++) {
            #pragma unroll
            for (int ni = 0; ni < 4; ni++) {
                int m = m0 + wrb + mi * 16 + lq * 4;
                int b = m >> 11, tt = m & (Tsz - 1);
                int n = (n0 & 1023) + wcb + ni * 16 + lr;
                int h = n >> 6, d = n & (HD - 1);
                uint2 pk;
                pk.x = pkbf(acc[mi][ni][0], acc[mi][ni][1]);
                pk.y = pkbf(acc[mi][ni][2], acc[mi][ni][3]);
                *(uint2*)(&Vo[(((size_t)b * NH + h) * HD + d) * Tsz + tt]) = pk;
            }
        }
    } else {
        const float scale = (sel == 0) ? qscale : 1.0f;
        u16* dst = (sel == 0) ? Qo : Ko;
        #pragma unroll
        for (int mi = 0; mi < 4; mi++)
            #pragma unroll
            for (int ni = 0; ni < 4; ni++)
                #pragma unroll
                for (int r = 0; r < 4; r++) {
                    int m = m0 + wrb + mi * 16 + lq * 4 + r;
                    int n = (n0 & 1023) + wcb + ni * 16 + lr;
                    int b = m >> 11, tt = m & (Tsz - 1);
                    int h = n >> 6,  d = n & (HD - 1);
                    dst[(((size_t)b * NH + h) * Tsz + tt) * HD + d] = f2bf(acc[mi][ni][r] * scale);
                }
    }
}

// ---------------- output projection GEMM ----------------
// Grid: 256 blocks (64 m-tiles x 4 n-tiles) = exactly 1 full round.
// Chunk = 8m x 4n per XCD (A 2MB + B 2MB = L2-fit).
__global__ __launch_bounds__(512, 2)
void gemm_out(const u16* __restrict__ A, const u16* __restrict__ Bm,
              float* __restrict__ out) {
    const int wg = blockIdx.x;
    const int chunk = wg & 7, pos = wg >> 3;            // pos 0..31
    const int m0 = (chunk * 8 + (pos >> 2)) * 128;
    const int n0 = (pos & 3) * 256;
    const u16* Ap = A  + (size_t)m0 * 1024;
    const u16* Bp = Bm + (size_t)n0 * 1024;

    G2_BODY(Ap, Bp)

    #pragma unroll
    for (int mi = 0; mi < 4; mi++)
        #pragma unroll
        for (int ni = 0; ni < 4; ni++)
            #pragma unroll
            for (int r = 0; r < 4; r++) {
                int m = m0 + wrb + mi * 16 + lq * 4 + r;
                int n = n0 + wcb + ni * 16 + lr;
                out[(size_t)m * Csz + n] = acc[mi][ni][r];
            }
}

// ---------------- flash attention ----------------
// Round-5 change: KVBLK 64 -> 128. One staging round (2 barriers) now covers
// TWO 64-k sub-tiles, halving barrier+drain rounds per block from 33 to ~17.
// The inner sub-loop is `#pragma unroll 1`, so PROCESS is still instantiated
// exactly twice (round-3's I-cache lesson). LDS: sK 128x72 (18.4KB) +
// sV 64x136 (17.4KB) + sP (8.7KB) = 44.5KB -> 3 blocks/CU (12 waves,
// >= measured 10.7). Prefetch registers double (pK[4], pV[4] bf16x8).
#define LDT  72
#define LDV  136
#define LDTP 68

__global__ __launch_bounds__(256, 4)
void attn_kernel(const u16* __restrict__ Q, const u16* __restrict__ Kb,
                 const u16* __restrict__ Vt, u16* __restrict__ O) {
    __shared__ u16 sK[128 * LDT];
    __shared__ u16 sV[64 * LDV];
    __shared__ u16 sP[4][16 * LDTP];
    const int tid  = threadIdx.x;
    const int wave = tid >> 6, lane = tid & 63;
    const int lr = lane & 15, lq = lane >> 4;
    const int bh = blockIdx.x;           // 0..63  (XCD swizzle: id%8 == bh%8)
    const int qa = blockIdx.y;           // 0..15  (short tile)
    const int qc = 31 - qa;              // 16..31 (long tile)
    const int ta = qa * 64, tc = qc * 64;

    const u16* Qp = Q  + (size_t)bh * Tsz * HD;
    const u16* Kp = Kb + (size_t)bh * Tsz * HD;
    const u16* Vp = Vt + (size_t)bh * HD * Tsz;

    bf16x8 qfA0 = *(const bf16x8*)(Qp + (size_t)(ta + wave * 16 + lr) * HD + lq * 8);
    bf16x8 qfA1 = *(const bf16x8*)(Qp + (size_t)(ta + wave * 16 + lr) * HD + 32 + lq * 8);
    bf16x8 qfC0 = *(const bf16x8*)(Qp + (size_t)(tc + wave * 16 + lr) * HD + lq * 8);
    bf16x8 qfC1 = *(const bf16x8*)(Qp + (size_t)(tc + wave * 16 + lr) * HD + 32 + lq * 8);

    f32x4 accOA[4] = {}, accOC[4] = {};
    f32x4 accLA = {}, accLC = {};

    bf16x8 ones;
    #pragma unroll
    for (int i = 0; i < 8; i++) ones[i] = (short)0x3F80;  // bf16 1.0

    // staging: 256 threads; K-tile 128 rows x 64 cols (rows strow+32q, q<4);
    // V-tile 64 rows x 128 cols (rows strow+32q q<2, cols stcol + 64h).
    const int strow = tid >> 3;          // 0..31
    const int stcol = (tid & 7) * 8;     // 0..56
    const u16* gK = Kp + (size_t)strow * HD + stcol;
    const u16* gV = Vp + (size_t)strow * Tsz + stcol;
    u16* lK = sK + strow * LDT + stcol;
    u16* lV = sV + strow * LDV + stcol;

    bf16x8 pK[4], pV[4];
    #pragma unroll
    for (int q = 0; q < 4; q++)
        pK[q] = *(const bf16x8*)(gK + (size_t)(32 * q) * HD);
    #pragma unroll
    for (int q = 0; q < 2; q++)
        #pragma unroll
        for (int h = 0; h < 2; h++)
            pV[q * 2 + h] = *(const bf16x8*)(gV + (size_t)(32 * q) * Tsz + 64 * h);

#define PROCESS(T0, QF0, QF1, ACCO, ACCL, KOFF, KBASE, DIAG)                          \
    {                                                                                 \
        f32x4 accS[4];                                                                \
        _Pragma("unroll")                                                             \
        for (int j = 0; j < 4; j++) {                                                 \
            bf16x8 b0 = *(const bf16x8*)(sK + ((KOFF) + j * 16 + lr) * LDT + lq * 8); \
            bf16x8 b1 = *(const bf16x8*)(sK + ((KOFF) + j * 16 + lr) * LDT + 32 + lq * 8); \
            f32x4 z = {};                                                             \
            z = __builtin_amdgcn_mfma_f32_16x16x32_bf16(QF0, b0, z, 0, 0, 0);         \
            z = __builtin_amdgcn_mfma_f32_16x16x32_bf16(QF1, b1, z, 0, 0, 0);         \
            accS[j] = z;                                                              \
        }                                                                             \
        _Pragma("unroll")                                                             \
        for (int r = 0; r < 4; r++) {                                                 \
            const int rowg = (T0) + wave * 16 + lq * 4 + r;                           \
            _Pragma("unroll")                                                         \
            for (int j = 0; j < 4; j++) {                                             \
                float v = accS[j][r];                                                 \
                if ((DIAG) && ((KBASE) + j * 16 + lr > rowg)) v = -200.0f;            \
                union { float f; uint u; } e;                                         \
                e.f = __builtin_amdgcn_exp2f(v);                                      \
                sP[wave][(lq * 4 + r) * LDTP + j * 16 + lr] = (u16)(e.u >> 16);       \
            }                                                                         \
        }                                                                             \
        _Pragma("unroll")                                                             \
        for (int ks = 0; ks < 2; ks++) {                                              \
            bf16x8 pf = *(const bf16x8*)(&sP[wave][0] + lr * LDTP + ks * 32 + lq * 8);\
            ACCL = __builtin_amdgcn_mfma_f32_16x16x32_bf16(pf, ones, ACCL, 0, 0, 0);  \
            _Pragma("unroll")                                                         \
            for (int j = 0; j < 4; j++) {                                             \
                bf16x8 vf = *(const bf16x8*)(sV + (j * 16 + lr) * LDV + (KOFF) + ks * 32 + lq * 8); \
                ACCO[j] = __builtin_amdgcn_mfma_f32_16x16x32_bf16(pf, vf, ACCO[j], 0, 0, 0); \
            }                                                                         \
        }                                                                             \
    }

    const int nround = (qc + 2) >> 1;    // ceil((qc+1)/2)
    for (int rr = 0; rr < nround; rr++) {
        __syncthreads();   // previous round's LDS reads complete
        #pragma unroll
        for (int q = 0; q < 4; q++)
            *(bf16x8*)(lK + (32 * q) * LDT) = pK[q];
        #pragma unroll
        for (int q = 0; q < 2; q++)
            #pragma unroll
            for (int h = 0; h < 2; h++)
                *(bf16x8*)(lV + (32 * q) * LDV + 64 * h) = pV[q * 2 + h];
        __syncthreads();
        if (rr + 1 < nround) {
            const u16* gKr = gK + (size_t)(rr + 1) * 128 * HD;
            const u16* gVr = gV + (rr + 1) * 128;
            #pragma unroll
            for (int q = 0; q < 4; q++)
                pK[q] = *(const bf16x8*)(gKr + (size_t)(32 * q) * HD);
            #pragma unroll
            for (int q = 0; q < 2; q++)
                #pragma unroll
                for (int h = 0; h < 2; h++)
                    pV[q * 2 + h] = *(const bf16x8*)(gVr + (size_t)(32 * q) * Tsz + 64 * h);
        }
        #pragma unroll 1
        for (int sub = 0; sub < 2; sub++) {
            const int kb = rr * 2 + sub;
            const int koff = sub * 64;
            if (kb <= qa) PROCESS(ta, qfA0, qfA1, accOA, accLA, koff, kb * 64, (kb == qa))
            if (kb <= qc) PROCESS(tc, qfC0, qfC1, accOC, accLC, koff, kb * 64, (kb == qc))
        }
    }
#undef PROCESS

    const int b = bh >> 4, h = bh & 15;
    #pragma unroll
    for (int j = 0; j < 4; j++) {
        #pragma unroll
        for (int r = 0; r < 4; r++) {
            int t = wave * 16 + lq * 4 + r;
            int d = j * 16 + lr;
            O[((size_t)b * Tsz + ta + t) * Csz + h * HD + d] = f2bf(accOA[j][r] / accLA[r]);
            O[((size_t)b * Tsz + tc + t) * Csz + h * HD + d] = f2bf(accOC[j][r] / accLC[r]);
        }
    }
}

// ---------------- launcher ----------------
extern "C" void kernel_launch(void* const* d_in, const int* in_sizes, int n_in,
                              void* d_out, int out_size, void* d_ws, size_t ws_size,
                              hipStream_t stream) {
    const float* x  = (const float*)d_in[0];
    const float* Wq = (const float*)d_in[1];
    const float* Wk = (const float*)d_in[2];
    const float* Wv = (const float*)d_in[3];
    const float* Wo = (const float*)d_in[4];
    float* out = (float*)d_out;

    const size_t NX = (size_t)Bsz * Tsz * Csz;  // 8388608
    const size_t NW = (size_t)Csz * Csz;        // 1048576

    char* ws = (char*)d_ws;
    u16* xb   = (u16*)ws; ws += NX * 2;
    u16* wqkv = (u16*)ws; ws += 3 * NW * 2;
    u16* wob  = (u16*)ws; ws += NW * 2;         // contiguous after wqkv (cast target)
    u16* qbuf = (u16*)ws; ws += NX * 2;
    u16* kbuf = (u16*)ws; ws += NX * 2;
    u16* vtb  = (u16*)ws; ws += NX * 2;
    u16* abuf = (u16*)ws; ws += NX * 2;

    cast_all<<<dim3((unsigned)((NX + 4 * NW) / 2048)), 256, 0, stream>>>(
        x, Wq, Wk, Wv, Wo, xb, wqkv);

    const float qscale = 0.125f * 1.44269504088896340736f;  // 1/sqrt(64) * log2(e)
    gemm_qkv<<<dim3(768), 512, 0, stream>>>(xb, wqkv, qbuf, kbuf, vtb, qscale);

    attn_kernel<<<dim3(Bsz * NH, 16), 256, 0, stream>>>(qbuf, kbuf, vtb, abuf);

    gemm_out<<<dim3(256), 512, 0, stream>>>(abuf, wob, out);
}

// Round 6
// 235.158 us; speedup vs baseline: 1.0975x; 1.0432x over previous
//
#include <hip/hip_runtime.h>
#include <math.h>

#define Bsz 4
#define Tsz 2048
#define Csz 1024
#define NH  16
#define HD  64

typedef short bf16x8 __attribute__((ext_vector_type(8)));
typedef float f32x4  __attribute__((ext_vector_type(4)));
typedef unsigned short u16;
typedef unsigned int uint;

__device__ __forceinline__ u16 f2bf(float f) {
    union { float f; unsigned u; } v; v.f = f;
    unsigned r = v.u + 0x7fffu + ((v.u >> 16) & 1u);
    return (u16)(r >> 16);
}

__device__ __forceinline__ uint pkbf(float a, float b) {
    union { float f; uint u; } x, y; x.f = a; y.f = b;
    return ((x.u + 0x8000u) >> 16) | ((y.u + 0x8000u) & 0xFFFF0000u);
}

// async global->LDS, 16B per lane. LDS dest is wave-uniform base + lane*16B.
__device__ __forceinline__ void glds16(const u16* g, u16* l) {
    __builtin_amdgcn_global_load_lds(
        (const __attribute__((address_space(1))) void*)g,
        (__attribute__((address_space(3))) void*)l, 16, 0, 0);
}

// ---------------- fused cast (x + 4 weight matrices, one launch) ----------------
// NX/8 elements-per-thread boundary = 1048576 = block 4096 exactly, so the
// source-select branch is block-uniform.
__global__ void cast_all(const float* __restrict__ x,
                         const float* __restrict__ s0, const float* __restrict__ s1,
                         const float* __restrict__ s2, const float* __restrict__ s3,
                         u16* __restrict__ xb, u16* __restrict__ wdst) {
    const int NW = Csz * Csz;
    const size_t NX = (size_t)Bsz * Tsz * Csz;
    size_t i = ((size_t)blockIdx.x * blockDim.x + threadIdx.x) * 8;
    const float* src;
    u16* dst;
    if (i < NX) {
        src = x + i; dst = xb + i;
    } else {
        size_t j = i - NX;
        int m = (int)(j >> 20);
        size_t local = j & (NW - 1);
        src = ((m == 0) ? s0 : (m == 1) ? s1 : (m == 2) ? s2 : s3) + local;
        dst = wdst + j;
    }
    float4 a = *(const float4*)(src);
    float4 b = *(const float4*)(src + 4);
    bf16x8 o;
    o[0] = (short)f2bf(a.x); o[1] = (short)f2bf(a.y);
    o[2] = (short)f2bf(a.z); o[3] = (short)f2bf(a.w);
    o[4] = (short)f2bf(b.x); o[5] = (short)f2bf(b.y);
    o[6] = (short)f2bf(b.z); o[7] = (short)f2bf(b.w);
    *(bf16x8*)(dst) = o;
}

// ================= 128x256 2-phase-per-K-tile GEMM template =================
// BM=128, BN=256, BK=64 (two k-halves of 32). 512 threads = 8 waves (2Mx4N),
// wave tile 64x64 = acc[4][4]. Per phase: read 4 A-frags + 4 B-frags, 16 MFMA.
// LDS: slot = A(16KB) + B(32KB) = 48KB; 2 slots = 96KB -> 1 block/CU.
//
// Stage granularity = one (matrix, khalf): A-half = 1 glds/thread, B-half = 2.
// Schedule: tile t ph0 stages (t+1,kh1,{A,B}) [3 loads]; ph1 stages
// (t+2,kh0,{A,B}) [3 loads]. Prologue: (0,kh0)(0,kh1)(1,kh0) = 9 loads.
// vmcnt ledger (per-wave counts; vmcnt BEFORE the barrier so every wave's own
// loads are complete, barrier publishes cross-wave):
//   t ph0 entry needs (t,kh0); newer outstanding = (t,kh1):3 + (t+1,kh0):3 -> vmcnt(6)
//   t ph1 entry needs (t,kh1); newer = (t+1,kh0):3 + (t+1,kh1):3 -> vmcnt(6)
//   t=15 ph0: newer = (15,kh1):3 -> vmcnt(3); t=15 ph1 -> vmcnt(0)
// Slot WAR: (t+1,kh1)->slot s^1 kh1, last read at t-1 ph1, all waves past t ph0
// barrier. (t+2,kh0)->slot s kh0, read at t ph0, all waves past t ph1 barrier.
// Bank swizzle (T2): 16B chunk c of row r stored at c^((r>>1)&3); applied on the
// glds GLOBAL source (LDS dest linear, rule 21) and XOR'd on the ds_read side.

#define G2_SS 24576   // u16: slot stride (48KB). A kh: SLOT*SS+KH*4096 (128x32)
                      // B kh: SLOT*SS+8192+KH*8192 (256x32)

#define G2_STAGEA(SLOT, KH, KT, PTR) {                                               \
    const int row_ = tid >> 2;                                                       \
    const int sc_ = (tid & 3) ^ ((row_ >> 1) & 3);                                   \
    glds16((PTR) + (size_t)row_ * 1024 + (KT) * 64 + (KH) * 32 + sc_ * 8,            \
           lds + (SLOT) * G2_SS + (KH) * 4096 + wave * 512); }

#define G2_STAGEB(SLOT, KH, KT, PTR) {                                               \
    _Pragma("unroll")                                                                \
    for (int rho = 0; rho < 2; rho++) {                                              \
        const int row_ = rho * 128 + (tid >> 2);                                     \
        const int sc_ = (tid & 3) ^ ((row_ >> 1) & 3);                               \
        glds16((PTR) + (size_t)row_ * 1024 + (KT) * 64 + (KH) * 32 + sc_ * 8,        \
               lds + (SLOT) * G2_SS + 8192 + (KH) * 8192 + rho * 4096 + wave * 512); } }

#define G2_PHASE(SLOT, KH, STAGE)                                                    \
    {                                                                                \
        __builtin_amdgcn_s_barrier();                                                \
        asm volatile("" ::: "memory");                                               \
        STAGE                                                                        \
        const u16* abase = lds + (SLOT) * G2_SS + (KH) * 4096;                       \
        const u16* bbase = lds + (SLOT) * G2_SS + 8192 + (KH) * 8192;                \
        bf16x8 afr[4], bfr[4];                                                       \
        _Pragma("unroll")                                                            \
        for (int i = 0; i < 4; i++) {                                                \
            const int ar = wrb + i * 16 + lr;                                        \
            afr[i] = *(const bf16x8*)(abase + ar * 32 +                              \
                                      ((lq ^ ((ar >> 1) & 3)) * 8));                 \
        }                                                                            \
        _Pragma("unroll")                                                            \
        for (int j = 0; j < 4; j++) {                                                \
            const int nr = wcb + j * 16 + lr;                                        \
            bfr[j] = *(const bf16x8*)(bbase + nr * 32 +                              \
                                      ((lq ^ ((nr >> 1) & 3)) * 8));                 \
        }                                                                            \
        asm volatile("" ::: "memory");                                               \
        __builtin_amdgcn_s_setprio(1);                                               \
        _Pragma("unroll")                                                            \
        for (int i = 0; i < 4; i++)                                                  \
            _Pragma("unroll")                                                        \
            for (int j = 0; j < 4; j++)                                              \
                acc[i][j] = __builtin_amdgcn_mfma_f32_16x16x32_bf16(                 \
                    afr[i], bfr[j], acc[i][j], 0, 0, 0);                             \
        __builtin_amdgcn_s_setprio(0);                                               \
    }

#define G2_VM(N) asm volatile("s_waitcnt vmcnt(" #N ")" ::: "memory")

#define G2_BODY(AP_, BP_)                                                            \
    __shared__ u16 lds[49152];                                                       \
    const int tid = threadIdx.x;                                                     \
    const int wave = tid >> 6, lane = tid & 63;                                      \
    const int lr = lane & 15, lq = lane >> 4;                                        \
    const int wrb = (wave >> 2) * 64, wcb = (wave & 3) * 64;                         \
    f32x4 acc[4][4] = {};                                                            \
    G2_STAGEA(0, 0, 0, AP_) G2_STAGEB(0, 0, 0, BP_)                                  \
    G2_STAGEA(0, 1, 0, AP_) G2_STAGEB(0, 1, 0, BP_)                                  \
    G2_STAGEA(1, 0, 1, AP_) G2_STAGEB(1, 0, 1, BP_)                                  \
    for (int t = 0; t < 16; t++) {                                                   \
        const int s = t & 1;                                                         \
        if (t == 15) { G2_VM(3); } else { G2_VM(6); }                                \
        G2_PHASE(s, 0, if (t < 15) { G2_STAGEA(s ^ 1, 1, t + 1, AP_)                 \
                                     G2_STAGEB(s ^ 1, 1, t + 1, BP_) })              \
        if (t == 15) { G2_VM(0); } else { G2_VM(6); }                                \
        G2_PHASE(s, 1, if (t < 14) { G2_STAGEA(s, 0, t + 2, AP_)                     \
                                     G2_STAGEB(s, 0, t + 2, BP_) })                  \
    }

// ---------------- fused QKV GEMM ----------------
// Grid: 768 flat blocks (64 m-tiles x 12 n-tiles) = 3 FULL dispatch rounds at
// 1 block/CU (no tail). XCD-chunked (768%8==0, bijective): chunk = 16m x 6n,
// n-fastest within (resident ~A 1.4MB + B 3MB ~ L2).
__global__ __launch_bounds__(512, 2)
void gemm_qkv(const u16* __restrict__ A, const u16* __restrict__ Bm,
              u16* __restrict__ Qo, u16* __restrict__ Ko, u16* __restrict__ Vo,
              float qscale) {
    const int wg = blockIdx.x;
    const int chunk = wg & 7, pos = wg >> 3;            // chunk = XCD, pos 0..95
    const int m0 = ((chunk >> 1) * 16 + pos / 6) * 128;
    const int n0 = ((chunk & 1) * 6 + pos % 6) * 256;
    const u16* Ap = A  + (size_t)m0 * 1024;
    const u16* Bp = Bm + (size_t)n0 * 1024;

    G2_BODY(Ap, Bp)

    const int sel = n0 >> 10;   // block-uniform: 0=Q, 1=K, 2=V
    if (sel == 2) {
        #pragma unroll
        for (int mi = 0; mi < 4; mi++) {
            #pragma unroll
            for (int ni = 0; ni < 4; ni++) {
                int m = m0 + wrb + mi * 16 + lq * 4;
                int b = m >> 11, tt = m & (Tsz - 1);
                int n = (n0 & 1023) + wcb + ni * 16 + lr;
                int h = n >> 6, d = n & (HD - 1);
                uint2 pk;
                pk.x = pkbf(acc[mi][ni][0], acc[mi][ni][1]);
                pk.y = pkbf(acc[mi][ni][2], acc[mi][ni][3]);
                *(uint2*)(&Vo[(((size_t)b * NH + h) * HD + d) * Tsz + tt]) = pk;
            }
        }
    } else {
        const float scale = (sel == 0) ? qscale : 1.0f;
        u16* dst = (sel == 0) ? Qo : Ko;
        #pragma unroll
        for (int mi = 0; mi < 4; mi++)
            #pragma unroll
            for (int ni = 0; ni < 4; ni++)
                #pragma unroll
                for (int r = 0; r < 4; r++) {
                    int m = m0 + wrb + mi * 16 + lq * 4 + r;
                    int n = (n0 & 1023) + wcb + ni * 16 + lr;
                    int b = m >> 11, tt = m & (Tsz - 1);
                    int h = n >> 6,  d = n & (HD - 1);
                    dst[(((size_t)b * NH + h) * Tsz + tt) * HD + d] = f2bf(acc[mi][ni][r] * scale);
                }
    }
}

// ---------------- output projection GEMM ----------------
// Grid: 256 blocks (64 m-tiles x 4 n-tiles) = exactly 1 full round.
// Chunk = 8m x 4n per XCD (A 2MB + B 2MB = L2-fit).
__global__ __launch_bounds__(512, 2)
void gemm_out(const u16* __restrict__ A, const u16* __restrict__ Bm,
              float* __restrict__ out) {
    const int wg = blockIdx.x;
    const int chunk = wg & 7, pos = wg >> 3;            // pos 0..31
    const int m0 = (chunk * 8 + (pos >> 2)) * 128;
    const int n0 = (pos & 3) * 256;
    const u16* Ap = A  + (size_t)m0 * 1024;
    const u16* Bp = Bm + (size_t)n0 * 1024;

    G2_BODY(Ap, Bp)

    #pragma unroll
    for (int mi = 0; mi < 4; mi++)
        #pragma unroll
        for (int ni = 0; ni < 4; ni++)
            #pragma unroll
            for (int r = 0; r < 4; r++) {
                int m = m0 + wrb + mi * 16 + lq * 4 + r;
                int n = n0 + wcb + ni * 16 + lr;
                out[(size_t)m * Csz + n] = acc[mi][ni][r];
            }
}

// ---------------- flash attention (round-4 measured-best version) ----------------
// KVBLK=64, LDT=72 pad (conflicts negligible: 0.02% of cycles), 2 PROCESS
// instantiations, runtime-uniform DIAG, no setprio. Measured 77.0 us.
// Round-5's KVBLK=128 regressed to 86.6 us (occupancy 33.7->25.1, VGPR 64->76):
// barrier-round savings < latency-hiding loss. Do not re-widen without
// restoring >=3 blocks/CU co-residency.
#define LDT  72
#define LDTP 68

__global__ __launch_bounds__(256, 4)
void attn_kernel(const u16* __restrict__ Q, const u16* __restrict__ Kb,
                 const u16* __restrict__ Vt, u16* __restrict__ O) {
    __shared__ u16 sK[64 * LDT];
    __shared__ u16 sV[64 * LDT];
    __shared__ u16 sP[4][16 * LDTP];
    const int tid  = threadIdx.x;
    const int wave = tid >> 6, lane = tid & 63;
    const int lr = lane & 15, lq = lane >> 4;
    const int bh = blockIdx.x;           // 0..63  (XCD swizzle: id%8 == bh%8)
    const int qa = blockIdx.y;           // 0..15  (short tile)
    const int qc = 31 - qa;              // 16..31 (long tile)
    const int ta = qa * 64, tc = qc * 64;

    const u16* Qp = Q  + (size_t)bh * Tsz * HD;
    const u16* Kp = Kb + (size_t)bh * Tsz * HD;
    const u16* Vp = Vt + (size_t)bh * HD * Tsz;

    bf16x8 qfA0 = *(const bf16x8*)(Qp + (size_t)(ta + wave * 16 + lr) * HD + lq * 8);
    bf16x8 qfA1 = *(const bf16x8*)(Qp + (size_t)(ta + wave * 16 + lr) * HD + 32 + lq * 8);
    bf16x8 qfC0 = *(const bf16x8*)(Qp + (size_t)(tc + wave * 16 + lr) * HD + lq * 8);
    bf16x8 qfC1 = *(const bf16x8*)(Qp + (size_t)(tc + wave * 16 + lr) * HD + 32 + lq * 8);

    f32x4 accOA[4] = {}, accOC[4] = {};
    f32x4 accLA = {}, accLC = {};

    bf16x8 ones;
    #pragma unroll
    for (int i = 0; i < 8; i++) ones[i] = (short)0x3F80;  // bf16 1.0

    const int strow = tid >> 3;
    const int stcol = (tid & 7) * 8;
    const u16* gK0 = Kp + (size_t)strow * HD + stcol;
    const u16* gK1 = gK0 + 32 * HD;
    const u16* gV0 = Vp + (size_t)strow * Tsz + stcol;
    const u16* gV1 = gV0 + 32 * Tsz;
    u16* lK0 = sK + strow * LDT + stcol;  u16* lK1 = lK0 + 32 * LDT;
    u16* lV0 = sV + strow * LDT + stcol;  u16* lV1 = lV0 + 32 * LDT;

    bf16x8 pK0 = *(const bf16x8*)(gK0);
    bf16x8 pK1 = *(const bf16x8*)(gK1);
    bf16x8 pV0 = *(const bf16x8*)(gV0);
    bf16x8 pV1 = *(const bf16x8*)(gV1);

#define PROCESS(T0, QF0, QF1, ACCO, ACCL, DIAG)                                       \
    {                                                                                 \
        f32x4 accS[4];                                                                \
        _Pragma("unroll")                                                             \
        for (int j = 0; j < 4; j++) {                                                 \
            bf16x8 b0 = *(const bf16x8*)(sK + (j * 16 + lr) * LDT + lq * 8);          \
            bf16x8 b1 = *(const bf16x8*)(sK + (j * 16 + lr) * LDT + 32 + lq * 8);     \
            f32x4 z = {};                                                             \
            z = __builtin_amdgcn_mfma_f32_16x16x32_bf16(QF0, b0, z, 0, 0, 0);         \
            z = __builtin_amdgcn_mfma_f32_16x16x32_bf16(QF1, b1, z, 0, 0, 0);         \
            accS[j] = z;                                                              \
        }                                                                             \
        _Pragma("unroll")                                                             \
        for (int r = 0; r < 4; r++) {                                                 \
            const int rowg = (T0) + wave * 16 + lq * 4 + r;                           \
            _Pragma("unroll")                                                         \
            for (int j = 0; j < 4; j++) {                                             \
                float v = accS[j][r];                                                 \
                if (DIAG && (kb * 64 + j * 16 + lr > rowg)) v = -200.0f;              \
                union { float f; uint u; } e;                                         \
                e.f = __builtin_amdgcn_exp2f(v);                                      \
                sP[wave][(lq * 4 + r) * LDTP + j * 16 + lr] = (u16)(e.u >> 16);       \
            }                                                                         \
        }                                                                             \
        _Pragma("unroll")                                                             \
        for (int ks = 0; ks < 2; ks++) {                                              \
            bf16x8 pf = *(const bf16x8*)(&sP[wave][0] + lr * LDTP + ks * 32 + lq * 8);\
            ACCL = __builtin_amdgcn_mfma_f32_16x16x32_bf16(pf, ones, ACCL, 0, 0, 0);  \
            _Pragma("unroll")                                                         \
            for (int j = 0; j < 4; j++) {                                             \
                bf16x8 vf = *(const bf16x8*)(sV + (j * 16 + lr) * LDT + ks * 32 + lq * 8); \
                ACCO[j] = __builtin_amdgcn_mfma_f32_16x16x32_bf16(pf, vf, ACCO[j], 0, 0, 0); \
            }                                                                         \
        }                                                                             \
    }

    for (int kb = 0; kb <= qc; kb++) {
        __syncthreads();
        *(bf16x8*)lK0 = pK0; *(bf16x8*)lK1 = pK1;
        *(bf16x8*)lV0 = pV0; *(bf16x8*)lV1 = pV1;
        __syncthreads();
        if (kb < qc) {
            pK0 = *(const bf16x8*)(gK0 + (size_t)(kb + 1) * 64 * HD);
            pK1 = *(const bf16x8*)(gK1 + (size_t)(kb + 1) * 64 * HD);
            pV0 = *(const bf16x8*)(gV0 + (kb + 1) * 64);
            pV1 = *(const bf16x8*)(gV1 + (kb + 1) * 64);
        }
        if (kb <= qa) PROCESS(ta, qfA0, qfA1, accOA, accLA, (kb == qa));
        PROCESS(tc, qfC0, qfC1, accOC, accLC, (kb == qc));
    }
#undef PROCESS

    const int b = bh >> 4, h = bh & 15;
    #pragma unroll
    for (int j = 0; j < 4; j++) {
        #pragma unroll
        for (int r = 0; r < 4; r++) {
            int t = wave * 16 + lq * 4 + r;
            int d = j * 16 + lr;
            O[((size_t)b * Tsz + ta + t) * Csz + h * HD + d] = f2bf(accOA[j][r] / accLA[r]);
            O[((size_t)b * Tsz + tc + t) * Csz + h * HD + d] = f2bf(accOC[j][r] / accLC[r]);
        }
    }
}

// ---------------- launcher ----------------
extern "C" void kernel_launch(void* const* d_in, const int* in_sizes, int n_in,
                              void* d_out, int out_size, void* d_ws, size_t ws_size,
                              hipStream_t stream) {
    const float* x  = (const float*)d_in[0];
    const float* Wq = (const float*)d_in[1];
    const float* Wk = (const float*)d_in[2];
    const float* Wv = (const float*)d_in[3];
    const float* Wo = (const float*)d_in[4];
    float* out = (float*)d_out;

    const size_t NX = (size_t)Bsz * Tsz * Csz;  // 8388608
    const size_t NW = (size_t)Csz * Csz;        // 1048576

    char* ws = (char*)d_ws;
    u16* xb   = (u16*)ws; ws += NX * 2;
    u16* wqkv = (u16*)ws; ws += 3 * NW * 2;
    u16* wob  = (u16*)ws; ws += NW * 2;         // contiguous after wqkv (cast target)
    u16* qbuf = (u16*)ws; ws += NX * 2;
    u16* kbuf = (u16*)ws; ws += NX * 2;
    u16* vtb  = (u16*)ws; ws += NX * 2;
    u16* abuf = (u16*)ws; ws += NX * 2;

    cast_all<<<dim3((unsigned)((NX + 4 * NW) / 2048)), 256, 0, stream>>>(
        x, Wq, Wk, Wv, Wo, xb, wqkv);

    const float qscale = 0.125f * 1.44269504088896340736f;  // 1/sqrt(64) * log2(e)
    gemm_qkv<<<dim3(768), 512, 0, stream>>>(xb, wqkv, qbuf, kbuf, vtb, qscale);

    attn_kernel<<<dim3(Bsz * NH, 16), 256, 0, stream>>>(qbuf, kbuf, vtb, abuf);

    gemm_out<<<dim3(256), 512, 0, stream>>>(abuf, wob, out);
}

// Round 7
// 233.362 us; speedup vs baseline: 1.1060x; 1.0077x over previous
//
#include <hip/hip_runtime.h>
#include <math.h>

#define Bsz 4
#define Tsz 2048
#define Csz 1024
#define NH  16
#define HD  64

typedef short bf16x8 __attribute__((ext_vector_type(8)));
typedef float f32x4  __attribute__((ext_vector_type(4)));
typedef unsigned short u16;
typedef unsigned int uint;

__device__ __forceinline__ u16 f2bf(float f) {
    union { float f; unsigned u; } v; v.f = f;
    unsigned r = v.u + 0x7fffu + ((v.u >> 16) & 1u);
    return (u16)(r >> 16);
}

__device__ __forceinline__ uint pkbf(float a, float b) {
    union { float f; uint u; } x, y; x.f = a; y.f = b;
    return ((x.u + 0x8000u) >> 16) | ((y.u + 0x8000u) & 0xFFFF0000u);
}

// async global->LDS, 16B per lane. LDS dest is wave-uniform base + lane*16B.
__device__ __forceinline__ void glds16(const u16* g, u16* l) {
    __builtin_amdgcn_global_load_lds(
        (const __attribute__((address_space(1))) void*)g,
        (__attribute__((address_space(3))) void*)l, 16, 0, 0);
}

// ---------------- fused cast (x + 4 weight matrices, one launch) ----------------
// NX/8 elements-per-thread boundary = 1048576 = block 4096 exactly, so the
// source-select branch is block-uniform.
__global__ void cast_all(const float* __restrict__ x,
                         const float* __restrict__ s0, const float* __restrict__ s1,
                         const float* __restrict__ s2, const float* __restrict__ s3,
                         u16* __restrict__ xb, u16* __restrict__ wdst) {
    const int NW = Csz * Csz;
    const size_t NX = (size_t)Bsz * Tsz * Csz;
    size_t i = ((size_t)blockIdx.x * blockDim.x + threadIdx.x) * 8;
    const float* src;
    u16* dst;
    if (i < NX) {
        src = x + i; dst = xb + i;
    } else {
        size_t j = i - NX;
        int m = (int)(j >> 20);
        size_t local = j & (NW - 1);
        src = ((m == 0) ? s0 : (m == 1) ? s1 : (m == 2) ? s2 : s3) + local;
        dst = wdst + j;
    }
    float4 a = *(const float4*)(src);
    float4 b = *(const float4*)(src + 4);
    bf16x8 o;
    o[0] = (short)f2bf(a.x); o[1] = (short)f2bf(a.y);
    o[2] = (short)f2bf(a.z); o[3] = (short)f2bf(a.w);
    o[4] = (short)f2bf(b.x); o[5] = (short)f2bf(b.y);
    o[6] = (short)f2bf(b.z); o[7] = (short)f2bf(b.w);
    *(bf16x8*)(dst) = o;
}

// ================= 128x256 2-phase-per-K-tile GEMM template =================
// BM=128, BN=256, BK=64 (two k-halves of 32). 512 threads = 8 waves (2Mx4N),
// wave tile 64x64 = acc[4][4]. Per phase: read 4 A-frags + 4 B-frags, 16 MFMA.
// LDS: slot = A(16KB) + B(32KB) = 48KB; 2 slots = 96KB -> 1 block/CU.
//
// Stage granularity = one (matrix, khalf): A-half = 1 glds/thread, B-half = 2.
// Schedule: tile t ph0 stages (t+1,kh1,{A,B}) [3 loads]; ph1 stages
// (t+2,kh0,{A,B}) [3 loads]. Prologue: (0,kh0)(0,kh1)(1,kh0) = 9 loads.
// vmcnt ledger (per-wave counts; vmcnt BEFORE the barrier so every wave's own
// loads are complete, barrier publishes cross-wave):
//   t ph0 entry needs (t,kh0); newer outstanding = (t,kh1):3 + (t+1,kh0):3 -> vmcnt(6)
//   t ph1 entry needs (t,kh1); newer = (t+1,kh0):3 + (t+1,kh1):3 -> vmcnt(6)
//   t=15 ph0: newer = (15,kh1):3 -> vmcnt(3); t=15 ph1 -> vmcnt(0)
// Slot WAR: (t+1,kh1)->slot s^1 kh1, last read at t-1 ph1, all waves past t ph0
// barrier. (t+2,kh0)->slot s kh0, read at t ph0, all waves past t ph1 barrier.
// Bank swizzle (T2): 16B chunk c of row r stored at c^((r>>1)&3); applied on the
// glds GLOBAL source (LDS dest linear, rule 21) and XOR'd on the ds_read side.

#define G2_SS 24576   // u16: slot stride (48KB). A kh: SLOT*SS+KH*4096 (128x32)
                      // B kh: SLOT*SS+8192+KH*8192 (256x32)

#define G2_STAGEA(SLOT, KH, KT, PTR) {                                               \
    const int row_ = tid >> 2;                                                       \
    const int sc_ = (tid & 3) ^ ((row_ >> 1) & 3);                                   \
    glds16((PTR) + (size_t)row_ * 1024 + (KT) * 64 + (KH) * 32 + sc_ * 8,            \
           lds + (SLOT) * G2_SS + (KH) * 4096 + wave * 512); }

#define G2_STAGEB(SLOT, KH, KT, PTR) {                                               \
    _Pragma("unroll")                                                                \
    for (int rho = 0; rho < 2; rho++) {                                              \
        const int row_ = rho * 128 + (tid >> 2);                                     \
        const int sc_ = (tid & 3) ^ ((row_ >> 1) & 3);                               \
        glds16((PTR) + (size_t)row_ * 1024 + (KT) * 64 + (KH) * 32 + sc_ * 8,        \
               lds + (SLOT) * G2_SS + 8192 + (KH) * 8192 + rho * 4096 + wave * 512); } }

#define G2_PHASE(SLOT, KH, STAGE)                                                    \
    {                                                                                \
        __builtin_amdgcn_s_barrier();                                                \
        asm volatile("" ::: "memory");                                               \
        STAGE                                                                        \
        const u16* abase = lds + (SLOT) * G2_SS + (KH) * 4096;                       \
        const u16* bbase = lds + (SLOT) * G2_SS + 8192 + (KH) * 8192;                \
        bf16x8 afr[4], bfr[4];                                                       \
        _Pragma("unroll")                                                            \
        for (int i = 0; i < 4; i++) {                                                \
            const int ar = wrb + i * 16 + lr;                                        \
            afr[i] = *(const bf16x8*)(abase + ar * 32 +                              \
                                      ((lq ^ ((ar >> 1) & 3)) * 8));                 \
        }                                                                            \
        _Pragma("unroll")                                                            \
        for (int j = 0; j < 4; j++) {                                                \
            const int nr = wcb + j * 16 + lr;                                        \
            bfr[j] = *(const bf16x8*)(bbase + nr * 32 +                              \
                                      ((lq ^ ((nr >> 1) & 3)) * 8));                 \
        }                                                                            \
        asm volatile("" ::: "memory");                                               \
        __builtin_amdgcn_s_setprio(1);                                               \
        _Pragma("unroll")                                                            \
        for (int i = 0; i < 4; i++)                                                  \
            _Pragma("unroll")                                                        \
            for (int j = 0; j < 4; j++)                                              \
                acc[i][j] = __builtin_amdgcn_mfma_f32_16x16x32_bf16(                 \
                    afr[i], bfr[j], acc[i][j], 0, 0, 0);                             \
        __builtin_amdgcn_s_setprio(0);                                               \
    }

#define G2_VM(N) asm volatile("s_waitcnt vmcnt(" #N ")" ::: "memory")

#define G2_BODY(AP_, BP_)                                                            \
    __shared__ u16 lds[49152];                                                       \
    const int tid = threadIdx.x;                                                     \
    const int wave = tid >> 6, lane = tid & 63;                                      \
    const int lr = lane & 15, lq = lane >> 4;                                        \
    const int wrb = (wave >> 2) * 64, wcb = (wave & 3) * 64;                         \
    f32x4 acc[4][4] = {};                                                            \
    G2_STAGEA(0, 0, 0, AP_) G2_STAGEB(0, 0, 0, BP_)                                  \
    G2_STAGEA(0, 1, 0, AP_) G2_STAGEB(0, 1, 0, BP_)                                  \
    G2_STAGEA(1, 0, 1, AP_) G2_STAGEB(1, 0, 1, BP_)                                  \
    for (int t = 0; t < 16; t++) {                                                   \
        const int s = t & 1;                                                         \
        if (t == 15) { G2_VM(3); } else { G2_VM(6); }                                \
        G2_PHASE(s, 0, if (t < 15) { G2_STAGEA(s ^ 1, 1, t + 1, AP_)                 \
                                     G2_STAGEB(s ^ 1, 1, t + 1, BP_) })              \
        if (t == 15) { G2_VM(0); } else { G2_VM(6); }                                \
        G2_PHASE(s, 1, if (t < 14) { G2_STAGEA(s, 0, t + 2, AP_)                     \
                                     G2_STAGEB(s, 0, t + 2, BP_) })                  \
    }

// ---------------- fused QKV GEMM ----------------
// Grid: 768 flat blocks (64 m-tiles x 12 n-tiles) = 3 FULL dispatch rounds at
// 1 block/CU (no tail). XCD-chunked (768%8==0, bijective): chunk = 16m x 6n,
// n-fastest within (resident ~A 1.4MB + B 3MB ~ L2).
__global__ __launch_bounds__(512, 2)
void gemm_qkv(const u16* __restrict__ A, const u16* __restrict__ Bm,
              u16* __restrict__ Qo, u16* __restrict__ Ko, u16* __restrict__ Vo,
              float qscale) {
    const int wg = blockIdx.x;
    const int chunk = wg & 7, pos = wg >> 3;            // chunk = XCD, pos 0..95
    const int m0 = ((chunk >> 1) * 16 + pos / 6) * 128;
    const int n0 = ((chunk & 1) * 6 + pos % 6) * 256;
    const u16* Ap = A  + (size_t)m0 * 1024;
    const u16* Bp = Bm + (size_t)n0 * 1024;

    G2_BODY(Ap, Bp)

    const int sel = n0 >> 10;   // block-uniform: 0=Q, 1=K, 2=V
    if (sel == 2) {
        #pragma unroll
        for (int mi = 0; mi < 4; mi++) {
            #pragma unroll
            for (int ni = 0; ni < 4; ni++) {
                int m = m0 + wrb + mi * 16 + lq * 4;
                int b = m >> 11, tt = m & (Tsz - 1);
                int n = (n0 & 1023) + wcb + ni * 16 + lr;
                int h = n >> 6, d = n & (HD - 1);
                uint2 pk;
                pk.x = pkbf(acc[mi][ni][0], acc[mi][ni][1]);
                pk.y = pkbf(acc[mi][ni][2], acc[mi][ni][3]);
                *(uint2*)(&Vo[(((size_t)b * NH + h) * HD + d) * Tsz + tt]) = pk;
            }
        }
    } else {
        const float scale = (sel == 0) ? qscale : 1.0f;
        u16* dst = (sel == 0) ? Qo : Ko;
        #pragma unroll
        for (int mi = 0; mi < 4; mi++)
            #pragma unroll
            for (int ni = 0; ni < 4; ni++)
                #pragma unroll
                for (int r = 0; r < 4; r++) {
                    int m = m0 + wrb + mi * 16 + lq * 4 + r;
                    int n = (n0 & 1023) + wcb + ni * 16 + lr;
                    int b = m >> 11, tt = m & (Tsz - 1);
                    int h = n >> 6,  d = n & (HD - 1);
                    dst[(((size_t)b * NH + h) * Tsz + tt) * HD + d] = f2bf(acc[mi][ni][r] * scale);
                }
    }
}

// ---------------- output projection GEMM ----------------
// Grid: 256 blocks (64 m-tiles x 4 n-tiles) = exactly 1 full round.
// Chunk = 8m x 4n per XCD (A 2MB + B 2MB = L2-fit).
__global__ __launch_bounds__(512, 2)
void gemm_out(const u16* __restrict__ A, const u16* __restrict__ Bm,
              float* __restrict__ out) {
    const int wg = blockIdx.x;
    const int chunk = wg & 7, pos = wg >> 3;            // pos 0..31
    const int m0 = (chunk * 8 + (pos >> 2)) * 128;
    const int n0 = (pos & 3) * 256;
    const u16* Ap = A  + (size_t)m0 * 1024;
    const u16* Bp = Bm + (size_t)n0 * 1024;

    G2_BODY(Ap, Bp)

    #pragma unroll
    for (int mi = 0; mi < 4; mi++)
        #pragma unroll
        for (int ni = 0; ni < 4; ni++)
            #pragma unroll
            for (int r = 0; r < 4; r++) {
                int m = m0 + wrb + mi * 16 + lq * 4 + r;
                int n = n0 + wcb + ni * 16 + lr;
                out[(size_t)m * Csz + n] = acc[mi][ni][r];
            }
}

// ---------------- flash attention ----------------
// Round-7 change: UNPAIRED q-tiles. Old grid (64 bh x 16 q-pairs) = 1024 blocks
// = only 4 blocks/CU of available work -> time-avg occupancy 35% (grid-capped,
// not resource-capped: LDS 27.1KB allows 5/CU). New grid (64 bh x 32 q-tiles)
// = 2048 blocks (8/CU available, 5/CU resident): occupancy cap moves to LDS.
// Long tiles dispatch first (tq = 31 - blockIdx.y, LPT) so short blocks
// backfill the tail. Per-block state halves (one qf/acc set). PROCESS math
// unchanged. Cost: +35% staging rounds and K/V L2 re-reads (HBM at 8.5%, ok).
#define LDT  72
#define LDTP 68

__global__ __launch_bounds__(256, 4)
void attn_kernel(const u16* __restrict__ Q, const u16* __restrict__ Kb,
                 const u16* __restrict__ Vt, u16* __restrict__ O) {
    __shared__ u16 sK[64 * LDT];
    __shared__ u16 sV[64 * LDT];
    __shared__ u16 sP[4][16 * LDTP];
    const int tid  = threadIdx.x;
    const int wave = tid >> 6, lane = tid & 63;
    const int lr = lane & 15, lq = lane >> 4;
    const int bh = blockIdx.x;           // 0..63  (XCD swizzle: id%8 == bh%8)
    const int tq = 31 - blockIdx.y;      // q-tile index; longest first (LPT)
    const int tc = tq * 64;

    const u16* Qp = Q  + (size_t)bh * Tsz * HD;
    const u16* Kp = Kb + (size_t)bh * Tsz * HD;
    const u16* Vp = Vt + (size_t)bh * HD * Tsz;

    bf16x8 qf0 = *(const bf16x8*)(Qp + (size_t)(tc + wave * 16 + lr) * HD + lq * 8);
    bf16x8 qf1 = *(const bf16x8*)(Qp + (size_t)(tc + wave * 16 + lr) * HD + 32 + lq * 8);

    f32x4 accO[4] = {};
    f32x4 accL = {};

    bf16x8 ones;
    #pragma unroll
    for (int i = 0; i < 8; i++) ones[i] = (short)0x3F80;  // bf16 1.0

    const int strow = tid >> 3;
    const int stcol = (tid & 7) * 8;
    const u16* gK0 = Kp + (size_t)strow * HD + stcol;
    const u16* gK1 = gK0 + 32 * HD;
    const u16* gV0 = Vp + (size_t)strow * Tsz + stcol;
    const u16* gV1 = gV0 + 32 * Tsz;
    u16* lK0 = sK + strow * LDT + stcol;  u16* lK1 = lK0 + 32 * LDT;
    u16* lV0 = sV + strow * LDT + stcol;  u16* lV1 = lV0 + 32 * LDT;

    bf16x8 pK0 = *(const bf16x8*)(gK0);
    bf16x8 pK1 = *(const bf16x8*)(gK1);
    bf16x8 pV0 = *(const bf16x8*)(gV0);
    bf16x8 pV1 = *(const bf16x8*)(gV1);

    for (int kb = 0; kb <= tq; kb++) {
        __syncthreads();   // previous iteration's LDS reads complete
        *(bf16x8*)lK0 = pK0; *(bf16x8*)lK1 = pK1;
        *(bf16x8*)lV0 = pV0; *(bf16x8*)lV1 = pV1;
        __syncthreads();
        if (kb < tq) {
            pK0 = *(const bf16x8*)(gK0 + (size_t)(kb + 1) * 64 * HD);
            pK1 = *(const bf16x8*)(gK1 + (size_t)(kb + 1) * 64 * HD);
            pV0 = *(const bf16x8*)(gV0 + (kb + 1) * 64);
            pV1 = *(const bf16x8*)(gV1 + (kb + 1) * 64);
        }
        {
            const int DIAG = (kb == tq);
            f32x4 accS[4];
            #pragma unroll
            for (int j = 0; j < 4; j++) {
                bf16x8 b0 = *(const bf16x8*)(sK + (j * 16 + lr) * LDT + lq * 8);
                bf16x8 b1 = *(const bf16x8*)(sK + (j * 16 + lr) * LDT + 32 + lq * 8);
                f32x4 z = {};
                z = __builtin_amdgcn_mfma_f32_16x16x32_bf16(qf0, b0, z, 0, 0, 0);
                z = __builtin_amdgcn_mfma_f32_16x16x32_bf16(qf1, b1, z, 0, 0, 0);
                accS[j] = z;
            }
            #pragma unroll
            for (int r = 0; r < 4; r++) {
                const int rowg = tc + wave * 16 + lq * 4 + r;
                #pragma unroll
                for (int j = 0; j < 4; j++) {
                    float v = accS[j][r];
                    if (DIAG && (kb * 64 + j * 16 + lr > rowg)) v = -200.0f;
                    union { float f; uint u; } e;
                    e.f = __builtin_amdgcn_exp2f(v);
                    sP[wave][(lq * 4 + r) * LDTP + j * 16 + lr] = (u16)(e.u >> 16);
                }
            }
            #pragma unroll
            for (int ks = 0; ks < 2; ks++) {
                bf16x8 pf = *(const bf16x8*)(&sP[wave][0] + lr * LDTP + ks * 32 + lq * 8);
                accL = __builtin_amdgcn_mfma_f32_16x16x32_bf16(pf, ones, accL, 0, 0, 0);
                #pragma unroll
                for (int j = 0; j < 4; j++) {
                    bf16x8 vf = *(const bf16x8*)(sV + (j * 16 + lr) * LDT + ks * 32 + lq * 8);
                    accO[j] = __builtin_amdgcn_mfma_f32_16x16x32_bf16(pf, vf, accO[j], 0, 0, 0);
                }
            }
        }
    }

    const int b = bh >> 4, h = bh & 15;
    #pragma unroll
    for (int j = 0; j < 4; j++) {
        #pragma unroll
        for (int r = 0; r < 4; r++) {
            int t = wave * 16 + lq * 4 + r;
            int d = j * 16 + lr;
            O[((size_t)b * Tsz + tc + t) * Csz + h * HD + d] = f2bf(accO[j][r] / accL[r]);
        }
    }
}

// ---------------- launcher ----------------
extern "C" void kernel_launch(void* const* d_in, const int* in_sizes, int n_in,
                              void* d_out, int out_size, void* d_ws, size_t ws_size,
                              hipStream_t stream) {
    const float* x  = (const float*)d_in[0];
    const float* Wq = (const float*)d_in[1];
    const float* Wk = (const float*)d_in[2];
    const float* Wv = (const float*)d_in[3];
    const float* Wo = (const float*)d_in[4];
    float* out = (float*)d_out;

    const size_t NX = (size_t)Bsz * Tsz * Csz;  // 8388608
    const size_t NW = (size_t)Csz * Csz;        // 1048576

    char* ws = (char*)d_ws;
    u16* xb   = (u16*)ws; ws += NX * 2;
    u16* wqkv = (u16*)ws; ws += 3 * NW * 2;
    u16* wob  = (u16*)ws; ws += NW * 2;         // contiguous after wqkv (cast target)
    u16* qbuf = (u16*)ws; ws += NX * 2;
    u16* kbuf = (u16*)ws; ws += NX * 2;
    u16* vtb  = (u16*)ws; ws += NX * 2;
    u16* abuf = (u16*)ws; ws += NX * 2;

    cast_all<<<dim3((unsigned)((NX + 4 * NW) / 2048)), 256, 0, stream>>>(
        x, Wq, Wk, Wv, Wo, xb, wqkv);

    const float qscale = 0.125f * 1.44269504088896340736f;  // 1/sqrt(64) * log2(e)
    gemm_qkv<<<dim3(768), 512, 0, stream>>>(xb, wqkv, qbuf, kbuf, vtb, qscale);

    attn_kernel<<<dim3(Bsz * NH, 32), 256, 0, stream>>>(qbuf, kbuf, vtb, abuf);

    gemm_out<<<dim3(256), 512, 0, stream>>>(abuf, wob, out);
}